// Round 2
// baseline (218627.563 us; speedup 1.0000x reference)
//
#include <hip/hip_runtime.h>
#include <math.h>

#define BB 64
#define LQ 1024
#define KVD 256
#define HD 512
#define ED 256
#define TT 300
#define VV 33
#define MHD 512
#define G4 2048
#define NBLK 1024

// ws float offsets
#define OFF_WPK     0L            // 6 x [128 k4][2048 r][4] packed gate weights
#define OFF_BIAS    6291456L      // 3*2048 combined bih+bhh, row r = m*4+g
#define OFF_WFC     6297600L      // [128 k4][256 kv][4]
#define OFF_WM1     6428672L      // [128 k4][512 m][4]
#define OFF_WM2T    6690816L      // [512][33]
#define OFF_WEMBT   6707712L      // [33][256]
#define OFF_H       6716160L      // [2 slot][3 layer][64][512]
#define OFF_C       6912768L
#define OFF_RNN     7109376L      // [2 slot][64][512]
#define OFF_P1      7174912L      // [64][2048]
#define OFF_P2      7305984L
#define OFF_QUERY   7437056L      // [64][256]
#define OFF_STATS   7453440L      // [64][16][2] (m, s per chunk)
#define OFF_CTXP    7455488L      // [64][16][256]
#define OFF_SCALES  7717632L      // [300][64][16]
#define OFF_BAR     8024832L      // 16 floats (barrier counter)
#define OFF_ATT     8024896L      // [300][64][1024] unnormalized p
#define WS_FLOATS_FULL 27685696L

// out float offsets
#define OUT_Y      0L
#define OUT_LBL    633600L
#define OUT_LPT    652800L
#define OUT_ATT    672000L

// ---------------- packing (once per call) ----------------
__global__ __launch_bounds__(256) void k_pack_gates(
    const float* __restrict__ Wih0, const float* __restrict__ Whh0,
    const float* __restrict__ Wih1, const float* __restrict__ Whh1,
    const float* __restrict__ Wih2, const float* __restrict__ Whh2,
    const float* __restrict__ bih0, const float* __restrict__ bhh0,
    const float* __restrict__ bih1, const float* __restrict__ bhh1,
    const float* __restrict__ bih2, const float* __restrict__ bhh2,
    float* __restrict__ ws)
{
    long id = (long)blockIdx.x * 256 + threadIdx.x;
    if (id < 6L * 262144L) {
        int mat = (int)(id / 262144L);
        int rem = (int)(id % 262144L);
        int k4 = rem >> 11;
        int r  = rem & 2047;
        int m = r >> 2, g = r & 3;
        int row = g * HD + m;
        const float* W = (mat==0)?Wih0:(mat==1)?Whh0:(mat==2)?Wih1:(mat==3)?Whh1:(mat==4)?Wih2:Whh2;
        const float4 v = *reinterpret_cast<const float4*>(W + (long)row * HD + k4 * 4);
        *reinterpret_cast<float4*>(ws + OFF_WPK + ((long)mat * 262144L + rem) * 4) = v;
    } else {
        long bid = id - 6L * 262144L;
        if (bid < 3L * 2048L) {
            int l = (int)(bid / 2048), r = (int)(bid % 2048);
            int m = r >> 2, g = r & 3;
            int row = g * HD + m;
            const float* bi = (l==0)?bih0:(l==1)?bih1:bih2;
            const float* bh = (l==0)?bhh0:(l==1)?bhh1:bhh2;
            ws[OFF_BIAS + bid] = bi[row] + bh[row];
        }
    }
}

__global__ __launch_bounds__(256) void k_pack_small(
    const float* __restrict__ W_fc, const float* __restrict__ W_mlp1,
    const float* __restrict__ W_mlp2, const float* __restrict__ W_emb,
    float* __restrict__ ws)
{
    int id = blockIdx.x * 256 + threadIdx.x;
    if (id < 32768) {
        int k4 = id >> 8, kv = id & 255;
        const float4 v = *reinterpret_cast<const float4*>(W_fc + (long)kv * HD + k4 * 4);
        *reinterpret_cast<float4*>(ws + OFF_WFC + (long)id * 4) = v;
        return;
    }
    id -= 32768;
    if (id < 65536) {
        int k4 = id >> 9, m = id & 511;
        const float4 v = *reinterpret_cast<const float4*>(W_mlp1 + (long)m * HD + k4 * 4);
        *reinterpret_cast<float4*>(ws + OFF_WM1 + (long)id * 4) = v;
        return;
    }
    id -= 65536;
    if (id < 512 * VV) {
        int m = id / VV, v = id % VV;
        ws[OFF_WM2T + id] = W_mlp2[(long)v * MHD + m];
        return;
    }
    id -= 512 * VV;
    if (id < VV * 256) {
        int v = id >> 8, e = id & 255;
        ws[OFF_WEMBT + id] = W_emb[(long)e * VV + v];
    }
}

__global__ __launch_bounds__(256) void k_init(
    const float* __restrict__ W_emb, const float* __restrict__ b_emb, float* __restrict__ ws)
{
    int id = blockIdx.x * 256 + threadIdx.x;
    if (id < 98304) { ws[OFF_H + id] = 0.f; ws[OFF_C + id] = 0.f; return; }
    id -= 98304;
    if (id < BB * HD) {
        int k = id & 511;
        float v = 0.f;
        if (k < ED) v = W_emb[(long)k * VV + 0] + b_emb[k];
        ws[OFF_RNN + id] = v;
    }
}

// ---------------- persistent loop kernel ----------------
struct SMGates { float in[32][132]; float g[8][33]; };
struct SMQuery { float h2[512]; float qp[4][64]; };
struct SMAttn  { float eL[64]; float pL[64]; };
struct SMFin   { float cat[512]; float hm[512]; float yp[4][33]; float sv[33]; float ysm[33]; float sc[16]; };
union SMU { SMGates g; SMQuery q; SMAttn a; SMFin f; };

__device__ __forceinline__ void gbar(unsigned* cnt, unsigned target)
{
    __syncthreads();
    if (threadIdx.x == 0) {
        __hip_atomic_fetch_add(cnt, 1u, __ATOMIC_ACQ_REL, __HIP_MEMORY_SCOPE_AGENT);
        while (__hip_atomic_load(cnt, __ATOMIC_RELAXED, __HIP_MEMORY_SCOPE_AGENT) < target)
            __builtin_amdgcn_s_sleep(2);
        __hip_atomic_fetch_add(cnt, 0u, __ATOMIC_ACQUIRE, __HIP_MEMORY_SCOPE_AGENT);
    }
    __syncthreads();
}

// 8 rows x 32 batch tile MAC: acc += (inp[32b x 512k] @ Wpk rows r0..r0+7)
__device__ __forceinline__ void gmac8(float& acc, const float* inp, const float* Wpk,
                                      int r0, int jl, int bg, float (*lin)[132], int tid)
{
    for (int kc = 0; kc < 4; ++kc) {
        __syncthreads();
        {
            int fid = tid;
            #pragma unroll
            for (int i = 0; i < 4; ++i, fid += 256) {
                int brow = fid >> 5, k4 = fid & 31;
                float4 v = *reinterpret_cast<const float4*>(inp + (long)brow * HD + kc * 128 + k4 * 4);
                *reinterpret_cast<float4*>(&lin[brow][k4 * 4]) = v;
            }
        }
        __syncthreads();
        const float* Wb = Wpk + ((long)(kc * 32) * G4 + (r0 + jl)) * 4;
        #pragma unroll 4
        for (int k4 = 0; k4 < 32; ++k4) {
            float4 w = *reinterpret_cast<const float4*>(Wb + (long)k4 * G4 * 4);
            float4 x = *reinterpret_cast<const float4*>(&lin[bg][k4 * 4]);
            acc += x.x * w.x + x.y * w.y + x.z * w.z + x.w * w.w;
        }
    }
}

__device__ __forceinline__ void cell8(float acc, int r0, int tid,
    const float* c_old, float* c_new, float* h_new, float (*g)[33])
{
    g[tid & 7][tid >> 3] = acc;
    __syncthreads();
    if (tid < 64) {
        int ml = tid >> 5, bl = tid & 31;
        int m = (r0 >> 2) + ml;
        float gi = g[ml * 4 + 0][bl];
        float gf = g[ml * 4 + 1][bl];
        float gg = g[ml * 4 + 2][bl];
        float go = g[ml * 4 + 3][bl];
        float si = 1.f / (1.f + expf(-gi));
        float sf = 1.f / (1.f + expf(-gf));
        float tg = tanhf(gg);
        float so = 1.f / (1.f + expf(-go));
        float c2 = sf * c_old[(long)bl * HD + m] + si * tg;
        c_new[(long)bl * HD + m] = c2;
        h_new[(long)bl * HD + m] = so * tanhf(c2);
    }
    __syncthreads();
}

__global__ __launch_bounds__(256, 4) void k_loop(
    const float* __restrict__ enc_key, const float* __restrict__ enc_value,
    const int* __restrict__ fsl, const float* __restrict__ gumbel_u,
    const float* __restrict__ b_fc, const float* __restrict__ b_mlp1,
    const float* __restrict__ b_mlp2, const float* __restrict__ b_emb,
    float* ws, float* out, float* attp, int attDirect)
{
    __shared__ SMU sm;
    int bx = blockIdx.x, tid = threadIdx.x;
    unsigned* bar = (unsigned*)(ws + OFF_BAR);
    unsigned bc = 0;

    for (int t = 0; t < TT; ++t) {
        int so = t & 1, sn = so ^ 1;

        // ---- PHASE A: L0 full gates + Whh partials L1,L2 ----
        if (bx < 512) {
            int px = bx >> 1, bh = bx & 1, r0 = px * 8;
            int jl = tid & 7, bg = tid >> 3;
            float acc = ws[OFF_BIAS + r0 + jl];
            const float* rnn = ws + OFF_RNN + (long)so * 32768 + (long)bh * 32 * HD;
            const float* h0  = ws + OFF_H + ((long)so * 3 + 0) * 32768 + (long)bh * 32 * HD;
            gmac8(acc, rnn, ws + OFF_WPK + 0L * 1048576L, r0, jl, bg, sm.g.in, tid);
            gmac8(acc, h0,  ws + OFF_WPK + 1L * 1048576L, r0, jl, bg, sm.g.in, tid);
            cell8(acc, r0, tid,
                  ws + OFF_C + ((long)so * 3 + 0) * 32768 + (long)bh * 32 * HD,
                  ws + OFF_C + ((long)sn * 3 + 0) * 32768 + (long)bh * 32 * HD,
                  ws + OFF_H + ((long)sn * 3 + 0) * 32768 + (long)bh * 32 * HD, sm.g.g);
        } else {
            int u = bx - 512;
            int px = u >> 1, bh = u & 1, r0 = px * 8;
            int jl = tid & 7, bg = tid >> 3;
            {
                float acc = ws[OFF_BIAS + 2048 + r0 + jl];
                const float* h1 = ws + OFF_H + ((long)so * 3 + 1) * 32768 + (long)bh * 32 * HD;
                gmac8(acc, h1, ws + OFF_WPK + 3L * 1048576L, r0, jl, bg, sm.g.in, tid);
                ws[OFF_P1 + (long)(bh * 32 + bg) * G4 + r0 + jl] = acc;
            }
            {
                float acc = ws[OFF_BIAS + 4096 + r0 + jl];
                const float* h2 = ws + OFF_H + ((long)so * 3 + 2) * 32768 + (long)bh * 32 * HD;
                gmac8(acc, h2, ws + OFF_WPK + 5L * 1048576L, r0, jl, bg, sm.g.in, tid);
                ws[OFF_P2 + (long)(bh * 32 + bg) * G4 + r0 + jl] = acc;
            }
        }
        gbar(bar, NBLK * (++bc));

        // ---- PHASE B: LSTM layer 1 ----
        if (bx < 512) {
            int px = bx >> 1, bh = bx & 1, r0 = px * 8;
            int jl = tid & 7, bg = tid >> 3;
            float acc = ws[OFF_P1 + (long)(bh * 32 + bg) * G4 + r0 + jl];
            const float* h0n = ws + OFF_H + ((long)sn * 3 + 0) * 32768 + (long)bh * 32 * HD;
            gmac8(acc, h0n, ws + OFF_WPK + 2L * 1048576L, r0, jl, bg, sm.g.in, tid);
            cell8(acc, r0, tid,
                  ws + OFF_C + ((long)so * 3 + 1) * 32768 + (long)bh * 32 * HD,
                  ws + OFF_C + ((long)sn * 3 + 1) * 32768 + (long)bh * 32 * HD,
                  ws + OFF_H + ((long)sn * 3 + 1) * 32768 + (long)bh * 32 * HD, sm.g.g);
        }
        gbar(bar, NBLK * (++bc));

        // ---- PHASE C: LSTM layer 2 ----
        if (bx < 512) {
            int px = bx >> 1, bh = bx & 1, r0 = px * 8;
            int jl = tid & 7, bg = tid >> 3;
            float acc = ws[OFF_P2 + (long)(bh * 32 + bg) * G4 + r0 + jl];
            const float* h1n = ws + OFF_H + ((long)sn * 3 + 1) * 32768 + (long)bh * 32 * HD;
            gmac8(acc, h1n, ws + OFF_WPK + 4L * 1048576L, r0, jl, bg, sm.g.in, tid);
            cell8(acc, r0, tid,
                  ws + OFF_C + ((long)so * 3 + 2) * 32768 + (long)bh * 32 * HD,
                  ws + OFF_C + ((long)sn * 3 + 2) * 32768 + (long)bh * 32 * HD,
                  ws + OFF_H + ((long)sn * 3 + 2) * 32768 + (long)bh * 32 * HD, sm.g.g);
        }
        gbar(bar, NBLK * (++bc));

        // ---- PHASE D: query = h2 @ Wfc^T + b_fc (256 units: b x kq) ----
        if (bx < 256) {
            int b = bx >> 2, kq = bx & 3;
            const float* h2p = ws + OFF_H + ((long)sn * 3 + 2) * 32768 + (long)b * HD;
            sm.q.h2[tid] = h2p[tid];
            sm.q.h2[tid + 256] = h2p[tid + 256];
            __syncthreads();
            int o = tid & 63, kh = tid >> 6;
            float acc = 0.f;
            const float* Wf = ws + OFF_WFC;
            #pragma unroll 4
            for (int k4i = 0; k4i < 32; ++k4i) {
                int k4 = kh * 32 + k4i;
                float4 wv = *reinterpret_cast<const float4*>(Wf + ((long)k4 * 256 + kq * 64 + o) * 4);
                float4 x  = *reinterpret_cast<const float4*>(&sm.q.h2[k4 * 4]);
                acc += x.x * wv.x + x.y * wv.y + x.z * wv.z + x.w * wv.w;
            }
            sm.q.qp[kh][o] = acc;
            __syncthreads();
            if (tid < 64) {
                float q = sm.q.qp[0][tid] + sm.q.qp[1][tid] + sm.q.qp[2][tid] + sm.q.qp[3][tid]
                          + b_fc[kq * 64 + tid];
                ws[OFF_QUERY + (long)b * 256 + kq * 64 + tid] = q;
            }
        }
        gbar(bar, NBLK * (++bc));

        // ---- PHASE E: attention single pass (1024 units: b x 16 chunks of 64 l) ----
        {
            int b = bx >> 4, ch = bx & 15, l0 = ch * 64;
            int lane = tid & 63, w = tid >> 6;
            int j = lane & 15, rq = lane >> 4;
            float4 q4[4];
            #pragma unroll
            for (int kk = 0; kk < 4; ++kk)
                q4[kk] = *reinterpret_cast<const float4*>(ws + OFF_QUERY + (long)b * 256 + kk * 64 + j * 4);
            int n = fsl[b];
            for (int qq = 0; qq < 4; ++qq) {
                int l = l0 + w * 16 + qq * 4 + rq;
                const float* Kr = enc_key + ((long)(b * LQ + l)) * KVD;
                float s = 0.f;
                #pragma unroll
                for (int kk = 0; kk < 4; ++kk) {
                    float4 kv = *reinterpret_cast<const float4*>(Kr + kk * 64 + j * 4);
                    s += kv.x * q4[kk].x + kv.y * q4[kk].y + kv.z * q4[kk].z + kv.w * q4[kk].w;
                }
                s += __shfl_xor(s, 1, 64); s += __shfl_xor(s, 2, 64);
                s += __shfl_xor(s, 4, 64); s += __shfl_xor(s, 8, 64);
                float e = (l < n) ? s : 0.f;   // softmax(energy*mask): masked -> exp(0)
                if (j == 0) sm.a.eL[w * 16 + qq * 4 + rq] = e;
            }
            __syncthreads();
            if (w == 0) {
                float e = sm.a.eL[lane];
                float m = e;
                m = fmaxf(m, __shfl_xor(m, 1, 64));  m = fmaxf(m, __shfl_xor(m, 2, 64));
                m = fmaxf(m, __shfl_xor(m, 4, 64));  m = fmaxf(m, __shfl_xor(m, 8, 64));
                m = fmaxf(m, __shfl_xor(m, 16, 64)); m = fmaxf(m, __shfl_xor(m, 32, 64));
                float p = expf(e - m);
                sm.a.pL[lane] = p;
                float su = p;
                su += __shfl_xor(su, 1, 64);  su += __shfl_xor(su, 2, 64);
                su += __shfl_xor(su, 4, 64);  su += __shfl_xor(su, 8, 64);
                su += __shfl_xor(su, 16, 64); su += __shfl_xor(su, 32, 64);
                if (attDirect) attp[((long)(b * LQ + l0 + lane)) * TT + t] = p;
                else           attp[(long)t * 65536 + b * LQ + l0 + lane] = p;
                if (lane == 0) {
                    ws[OFF_STATS + ((long)(b * 16 + ch)) * 2 + 0] = m;
                    ws[OFF_STATS + ((long)(b * 16 + ch)) * 2 + 1] = su;
                }
            }
            __syncthreads();
            float acc = 0.f;
            const float* Vb = enc_value + ((long)(b * LQ + l0)) * KVD + tid;
            #pragma unroll 8
            for (int i = 0; i < 64; ++i) acc += sm.a.pL[i] * Vb[(long)i * KVD];
            ws[OFF_CTXP + ((long)(b * 16 + ch)) * 256 + tid] = acc;
        }
        gbar(bar, NBLK * (++bc));

        // ---- PHASE F: combine + MLP + gumbel + argmax + emb (64 units) ----
        if (bx < 64) {
            int b = bx;
            const float* st = ws + OFF_STATS + (long)b * 32;
            if (tid == 0) {
                float M = -3.4e38f;
                for (int i = 0; i < 16; ++i) M = fmaxf(M, st[i * 2]);
                float S = 0.f;
                for (int i = 0; i < 16; ++i) S += st[i * 2 + 1] * expf(st[i * 2] - M);
                float iS = 1.f / S;
                for (int i = 0; i < 16; ++i) sm.f.sc[i] = expf(st[i * 2] - M) * iS;
            }
            __syncthreads();
            if (tid < 16) ws[OFF_SCALES + ((long)t * 64 + b) * 16 + tid] = sm.f.sc[tid];
            float ctx = 0.f;
            #pragma unroll
            for (int i = 0; i < 16; ++i)
                ctx += sm.f.sc[i] * ws[OFF_CTXP + ((long)(b * 16 + i)) * 256 + tid];
            sm.f.cat[256 + tid] = ctx;
            sm.f.cat[tid] = ws[OFF_QUERY + (long)b * 256 + tid];
            ws[OFF_RNN + (long)sn * 32768 + (long)b * HD + 256 + tid] = ctx;
            __syncthreads();
            float a0 = b_mlp1[tid], a1 = b_mlp1[tid + 256];
            const float* Wm1 = ws + OFF_WM1;
            #pragma unroll 2
            for (int k4 = 0; k4 < 128; ++k4) {
                float4 x  = *reinterpret_cast<const float4*>(&sm.f.cat[k4 * 4]);
                float4 wA = *reinterpret_cast<const float4*>(Wm1 + ((long)k4 * 512 + tid) * 4);
                float4 wB = *reinterpret_cast<const float4*>(Wm1 + ((long)k4 * 512 + tid + 256) * 4);
                a0 += x.x * wA.x + x.y * wA.y + x.z * wA.z + x.w * wA.w;
                a1 += x.x * wB.x + x.y * wB.y + x.z * wB.z + x.w * wB.w;
            }
            sm.f.hm[tid]       = (a0 >= 0.f) ? a0 : 0.9f * a0;
            sm.f.hm[tid + 256] = (a1 >= 0.f) ? a1 : 0.9f * a1;
            __syncthreads();
            int w = tid >> 6, lane = tid & 63;
            if (lane < VV) {
                float acc = 0.f;
                const float* W2 = ws + OFF_WM2T;
                for (int m = w * 128; m < w * 128 + 128; ++m) acc += sm.f.hm[m] * W2[(long)m * VV + lane];
                sm.f.yp[w][lane] = acc;
            }
            __syncthreads();
            if (tid < VV) {
                float y = sm.f.yp[0][tid] + sm.f.yp[1][tid] + sm.f.yp[2][tid] + sm.f.yp[3][tid] + b_mlp2[tid];
                out[OUT_Y + ((long)b * TT + t) * VV + tid] = y;
                float u = gumbel_u[((long)t * BB + b) * VV + tid];
                float g = -logf(-logf(u + 1e-10f) + 1e-10f);
                sm.f.sv[tid] = y + g;
            }
            __syncthreads();
            if (tid == 0) {
                float mx = sm.f.sv[0]; int am = 0;
                for (int v = 1; v < VV; ++v) if (sm.f.sv[v] > mx) { mx = sm.f.sv[v]; am = v; }
                float Z = 0.f;
                for (int v = 0; v < VV; ++v) { float p = expf(sm.f.sv[v] - mx); sm.f.ysm[v] = p; Z += p; }
                float iz = 1.f / Z;
                for (int v = 0; v < VV; ++v) sm.f.ysm[v] *= iz;
                out[OUT_LBL + (long)b * TT + t] = (float)am;
            }
            __syncthreads();
            float acc = b_emb[tid];
            const float* We = ws + OFF_WEMBT;
            #pragma unroll
            for (int v = 0; v < VV; ++v) acc += sm.f.ysm[v] * We[(long)v * 256 + tid];
            ws[OFF_RNN + (long)sn * 32768 + (long)b * HD + tid] = acc;
        }
        gbar(bar, NBLK * (++bc));
    }
}

// ---------------- epilogues ----------------
__global__ __launch_bounds__(256) void k_labels(const int* __restrict__ lp, float* __restrict__ out)
{
    int id = blockIdx.x * 256 + threadIdx.x;
    if (id < BB * TT) {
        int b = id / TT, t = id % TT;
        out[OUT_LPT + id] = (float)lp[(long)t * BB + b];
    }
}

// full path: normalize (p * scale) + transpose [t][b*1024+l] -> out [b][l][t]
__global__ __launch_bounds__(256) void k_att_fin(const float* __restrict__ ws_ro,
                                                 float* __restrict__ out)
{
    __shared__ float tile[32][33];
    int blt = blockIdx.x, ttb = blockIdx.y;
    int tx = threadIdx.x & 31, ty = threadIdx.x >> 5;
    int bl0 = blt * 32, t0 = ttb * 32;
    int b = bl0 >> 10, ch = (bl0 & 1023) >> 6;
    #pragma unroll
    for (int jj = 0; jj < 4; ++jj) {
        int trow = t0 + ty + jj * 8;
        if (trow < TT) {
            float s = ws_ro[OFF_SCALES + ((long)trow * 64 + b) * 16 + ch];
            tile[ty + jj * 8][tx] = ws_ro[OFF_ATT + (long)trow * 65536 + bl0 + tx] * s;
        }
    }
    __syncthreads();
    #pragma unroll
    for (int jj = 0; jj < 4; ++jj) {
        int row = bl0 + ty + jj * 8;
        int col = t0 + tx;
        if (col < TT) out[OUT_ATT + (long)row * TT + col] = tile[tx][ty + jj * 8];
    }
}

// direct path: in-place scale of out[b][l][t]
__global__ __launch_bounds__(320) void k_att_scale(const float* __restrict__ ws_ro,
                                                    float* __restrict__ out)
{
    int bl = blockIdx.x;  // b*1024 + l
    int b = bl >> 10, ch = (bl & 1023) >> 6;
    int tid = threadIdx.x;
    if (tid < TT) {
        long base = OUT_ATT + (long)bl * TT;
        out[base + tid] *= ws_ro[OFF_SCALES + ((long)tid * 64 + b) * 16 + ch];
    }
}

extern "C" void kernel_launch(void* const* d_in, const int* in_sizes, int n_in,
                              void* d_out, int out_size, void* d_ws, size_t ws_size,
                              hipStream_t stream)
{
    const float* enc_key   = (const float*)d_in[0];
    const float* enc_value = (const float*)d_in[1];
    const int*   labels    = (const int*)d_in[2];
    const int*   fsl       = (const int*)d_in[3];
    const float* gumbel_u  = (const float*)d_in[4];
    const float* W_emb     = (const float*)d_in[5];
    const float* b_emb     = (const float*)d_in[6];
    const float* W_fc      = (const float*)d_in[7];
    const float* b_fc      = (const float*)d_in[8];
    const float* W_mlp1    = (const float*)d_in[9];
    const float* b_mlp1    = (const float*)d_in[10];
    const float* W_mlp2    = (const float*)d_in[11];
    const float* b_mlp2    = (const float*)d_in[12];
    const float* Wih0 = (const float*)d_in[13];
    const float* Whh0 = (const float*)d_in[14];
    const float* bih0 = (const float*)d_in[15];
    const float* bhh0 = (const float*)d_in[16];
    const float* Wih1 = (const float*)d_in[17];
    const float* Whh1 = (const float*)d_in[18];
    const float* bih1 = (const float*)d_in[19];
    const float* bhh1 = (const float*)d_in[20];
    const float* Wih2 = (const float*)d_in[21];
    const float* Whh2 = (const float*)d_in[22];
    const float* bih2 = (const float*)d_in[23];
    const float* bhh2 = (const float*)d_in[24];
    float* ws  = (float*)d_ws;
    float* out = (float*)d_out;

    const bool full = ws_size >= (size_t)WS_FLOATS_FULL * 4;
    float* attp = full ? (ws + OFF_ATT) : (out + OUT_ATT);
    const int attDirect = full ? 0 : 1;

    hipMemsetAsync((char*)d_ws + OFF_BAR * 4, 0, 64, stream);
    hipLaunchKernelGGL(k_pack_gates, dim3(6168), dim3(256), 0, stream,
                       Wih0, Whh0, Wih1, Whh1, Wih2, Whh2,
                       bih0, bhh0, bih1, bhh1, bih2, bhh2, ws);
    hipLaunchKernelGGL(k_pack_small, dim3(483), dim3(256), 0, stream,
                       W_fc, W_mlp1, W_mlp2, W_emb, ws);
    hipLaunchKernelGGL(k_init, dim3(512), dim3(256), 0, stream, W_emb, b_emb, ws);

    hipLaunchKernelGGL(k_loop, dim3(NBLK), dim3(256), 0, stream,
                       enc_key, enc_value, fsl, gumbel_u, b_fc, b_mlp1, b_mlp2, b_emb,
                       ws, out, attp, attDirect);

    hipLaunchKernelGGL(k_labels, dim3(75), dim3(256), 0, stream, labels, out);
    if (full) hipLaunchKernelGGL(k_att_fin, dim3(2048, 10), dim3(256), 0, stream, ws, out);
    else      hipLaunchKernelGGL(k_att_scale, dim3(65536), dim3(320), 0, stream, ws, out);
}

// Round 3
// 150936.816 us; speedup vs baseline: 1.4485x; 1.4485x over previous
//
#include <hip/hip_runtime.h>
#include <math.h>

#define BB 64
#define LQ 1024
#define KVD 256
#define HD 512
#define ED 256
#define TT 300
#define VV 33
#define MHD 512
#define G4 2048
#define NBLK 1024
#define NGRP 32
#define GSZ 32

// ws float offsets
#define OFF_WPK     0L            // 6 x [128 k4][2048 r][4] packed gate weights
#define OFF_BIAS    6291456L      // 3*2048 combined bih+bhh, row r = m*4+g
#define OFF_WFC     6297600L      // [128 k4][256 kv][4]
#define OFF_WM1     6428672L      // [128 k4][512 m][4]
#define OFF_WM2T    6690816L      // [512][33]
#define OFF_WEMBT   6707712L      // [33][256]
#define OFF_H       6716160L      // [2 slot][3 layer][64][512]
#define OFF_C       6912768L
#define OFF_RNN     7109376L      // [2 slot][64][512]
#define OFF_P1      7174912L      // [64][2048]
#define OFF_P2      7305984L
#define OFF_QUERY   7437056L      // [64][256]
#define OFF_STATS   7453440L      // [64][16][2] (m, s per chunk)
#define OFF_CTXP    7455488L      // [64][16][256]
#define OFF_SCALES  7717632L      // [300][64][16]
#define OFF_BAR     8024832L      // tree barrier: 4224 floats (slots spaced 64 floats)
#define OFF_ATT     8029056L      // [300][64][1024] unnormalized p
#define WS_FLOATS_FULL 27689856L

// out float offsets
#define OUT_Y      0L
#define OUT_LBL    633600L
#define OUT_LPT    652800L
#define OUT_ATT    672000L

// ---------------- packing (once per call) ----------------
__global__ __launch_bounds__(256) void k_pack_gates(
    const float* __restrict__ Wih0, const float* __restrict__ Whh0,
    const float* __restrict__ Wih1, const float* __restrict__ Whh1,
    const float* __restrict__ Wih2, const float* __restrict__ Whh2,
    const float* __restrict__ bih0, const float* __restrict__ bhh0,
    const float* __restrict__ bih1, const float* __restrict__ bhh1,
    const float* __restrict__ bih2, const float* __restrict__ bhh2,
    float* __restrict__ ws)
{
    long id = (long)blockIdx.x * 256 + threadIdx.x;
    if (id < 6L * 262144L) {
        int mat = (int)(id / 262144L);
        int rem = (int)(id % 262144L);
        int k4 = rem >> 11;
        int r  = rem & 2047;
        int m = r >> 2, g = r & 3;
        int row = g * HD + m;
        const float* W = (mat==0)?Wih0:(mat==1)?Whh0:(mat==2)?Wih1:(mat==3)?Whh1:(mat==4)?Wih2:Whh2;
        const float4 v = *reinterpret_cast<const float4*>(W + (long)row * HD + k4 * 4);
        *reinterpret_cast<float4*>(ws + OFF_WPK + ((long)mat * 262144L + rem) * 4) = v;
    } else {
        long bid = id - 6L * 262144L;
        if (bid < 3L * 2048L) {
            int l = (int)(bid / 2048), r = (int)(bid % 2048);
            int m = r >> 2, g = r & 3;
            int row = g * HD + m;
            const float* bi = (l==0)?bih0:(l==1)?bih1:bih2;
            const float* bh = (l==0)?bhh0:(l==1)?bhh1:bhh2;
            ws[OFF_BIAS + bid] = bi[row] + bh[row];
        }
    }
}

__global__ __launch_bounds__(256) void k_pack_small(
    const float* __restrict__ W_fc, const float* __restrict__ W_mlp1,
    const float* __restrict__ W_mlp2, const float* __restrict__ W_emb,
    float* __restrict__ ws)
{
    int id = blockIdx.x * 256 + threadIdx.x;
    if (id < 32768) {
        int k4 = id >> 8, kv = id & 255;
        const float4 v = *reinterpret_cast<const float4*>(W_fc + (long)kv * HD + k4 * 4);
        *reinterpret_cast<float4*>(ws + OFF_WFC + (long)id * 4) = v;
        return;
    }
    id -= 32768;
    if (id < 65536) {
        int k4 = id >> 9, m = id & 511;
        const float4 v = *reinterpret_cast<const float4*>(W_mlp1 + (long)m * HD + k4 * 4);
        *reinterpret_cast<float4*>(ws + OFF_WM1 + (long)id * 4) = v;
        return;
    }
    id -= 65536;
    if (id < 512 * VV) {
        int m = id / VV, v = id % VV;
        ws[OFF_WM2T + id] = W_mlp2[(long)v * MHD + m];
        return;
    }
    id -= 512 * VV;
    if (id < VV * 256) {
        int v = id >> 8, e = id & 255;
        ws[OFF_WEMBT + id] = W_emb[(long)e * VV + v];
    }
}

__global__ __launch_bounds__(256) void k_init(
    const float* __restrict__ W_emb, const float* __restrict__ b_emb, float* __restrict__ ws)
{
    int id = blockIdx.x * 256 + threadIdx.x;
    if (id < 98304) { ws[OFF_H + id] = 0.f; ws[OFF_C + id] = 0.f; return; }
    id -= 98304;
    if (id < BB * HD) {
        int k = id & 511;
        float v = 0.f;
        if (k < ED) v = W_emb[(long)k * VV + 0] + b_emb[k];
        ws[OFF_RNN + id] = v;
    }
}

// ---------------- persistent loop kernel ----------------
struct SMGates { float in[32][132]; float g[8][33]; };
struct SMQuery { float h2[512]; float qp[4][64]; };
struct SMAttn  { float eL[64]; float pL[64]; };
struct SMFin   { float cat[512]; float hm[512]; float yp[4][33]; float sv[33]; float ysm[33]; float sc[16]; };
union SMU { SMGates g; SMQuery q; SMAttn a; SMFin f; };

// Two-level tree barrier: 32 groups x 32 blocks. Each counter/flag on its own
// 256B line. Data fencing: one __threadfence() pair per block at the endpoints
// (release before arrival, acquire after go); tree signals are relaxed.
__device__ __forceinline__ void gbar(float* wsbar, int bx, unsigned bc)
{
    __syncthreads();
    if (threadIdx.x == 0) {
        __threadfence();   // release: flush this XCD's L2 (prior stores -> coherence point)
        unsigned* rootCnt = (unsigned*)(wsbar);
        unsigned* rootGo  = (unsigned*)(wsbar + 64);
        int g = bx & (NGRP - 1);
        unsigned* grpCnt = (unsigned*)(wsbar + 128 + (long)g * 64);
        unsigned* grpGo  = (unsigned*)(wsbar + 128 + (long)NGRP * 64 + (long)g * 64);
        unsigned old = __hip_atomic_fetch_add(grpCnt, 1u, __ATOMIC_RELAXED, __HIP_MEMORY_SCOPE_AGENT);
        if (old == GSZ * bc - 1) {             // last arriver of this group, this epoch
            unsigned ro = __hip_atomic_fetch_add(rootCnt, 1u, __ATOMIC_RELAXED, __HIP_MEMORY_SCOPE_AGENT);
            if (ro == NGRP * bc - 1) {         // globally last
                __hip_atomic_store(rootGo, bc, __ATOMIC_RELAXED, __HIP_MEMORY_SCOPE_AGENT);
            } else {
                while (__hip_atomic_load(rootGo, __ATOMIC_RELAXED, __HIP_MEMORY_SCOPE_AGENT) < bc)
                    __builtin_amdgcn_s_sleep(2);
            }
            __hip_atomic_store(grpGo, bc, __ATOMIC_RELAXED, __HIP_MEMORY_SCOPE_AGENT);
        } else {
            while (__hip_atomic_load(grpGo, __ATOMIC_RELAXED, __HIP_MEMORY_SCOPE_AGENT) < bc)
                __builtin_amdgcn_s_sleep(2);
        }
        __threadfence();   // acquire: invalidate stale L1/L2 lines before reading others' data
    }
    __syncthreads();
}

// 8 rows x 32 batch tile MAC: acc += (inp[32b x 512k] @ Wpk rows r0..r0+7)
__device__ __forceinline__ void gmac8(float& acc, const float* inp, const float* Wpk,
                                      int r0, int jl, int bg, float (*lin)[132], int tid)
{
    for (int kc = 0; kc < 4; ++kc) {
        __syncthreads();
        {
            int fid = tid;
            #pragma unroll
            for (int i = 0; i < 4; ++i, fid += 256) {
                int brow = fid >> 5, k4 = fid & 31;
                float4 v = *reinterpret_cast<const float4*>(inp + (long)brow * HD + kc * 128 + k4 * 4);
                *reinterpret_cast<float4*>(&lin[brow][k4 * 4]) = v;
            }
        }
        __syncthreads();
        const float* Wb = Wpk + ((long)(kc * 32) * G4 + (r0 + jl)) * 4;
        #pragma unroll 4
        for (int k4 = 0; k4 < 32; ++k4) {
            float4 w = *reinterpret_cast<const float4*>(Wb + (long)k4 * G4 * 4);
            float4 x = *reinterpret_cast<const float4*>(&lin[bg][k4 * 4]);
            acc += x.x * w.x + x.y * w.y + x.z * w.z + x.w * w.w;
        }
    }
}

__device__ __forceinline__ void cell8(float acc, int r0, int tid,
    const float* c_old, float* c_new, float* h_new, float (*g)[33])
{
    g[tid & 7][tid >> 3] = acc;
    __syncthreads();
    if (tid < 64) {
        int ml = tid >> 5, bl = tid & 31;
        int m = (r0 >> 2) + ml;
        float gi = g[ml * 4 + 0][bl];
        float gf = g[ml * 4 + 1][bl];
        float gg = g[ml * 4 + 2][bl];
        float go = g[ml * 4 + 3][bl];
        float si = 1.f / (1.f + expf(-gi));
        float sf = 1.f / (1.f + expf(-gf));
        float tg = tanhf(gg);
        float so = 1.f / (1.f + expf(-go));
        float c2 = sf * c_old[(long)bl * HD + m] + si * tg;
        c_new[(long)bl * HD + m] = c2;
        h_new[(long)bl * HD + m] = so * tanhf(c2);
    }
    __syncthreads();
}

__global__ __launch_bounds__(256, 4) void k_loop(
    const float* __restrict__ enc_key, const float* __restrict__ enc_value,
    const int* __restrict__ fsl, const float* __restrict__ gumbel_u,
    const float* __restrict__ b_fc, const float* __restrict__ b_mlp1,
    const float* __restrict__ b_mlp2, const float* __restrict__ b_emb,
    float* ws, float* out, float* attp, int attDirect)
{
    __shared__ SMU sm;
    int bx = blockIdx.x, tid = threadIdx.x;
    float* wsbar = ws + OFF_BAR;
    unsigned bc = 0;

    for (int t = 0; t < TT; ++t) {
        int so = t & 1, sn = so ^ 1;

        // ---- PHASE A: L0 full gates + Whh partials L1,L2 ----
        if (bx < 512) {
            int px = bx >> 1, bh = bx & 1, r0 = px * 8;
            int jl = tid & 7, bg = tid >> 3;
            float acc = ws[OFF_BIAS + r0 + jl];
            const float* rnn = ws + OFF_RNN + (long)so * 32768 + (long)bh * 32 * HD;
            const float* h0  = ws + OFF_H + ((long)so * 3 + 0) * 32768 + (long)bh * 32 * HD;
            gmac8(acc, rnn, ws + OFF_WPK + 0L * 1048576L, r0, jl, bg, sm.g.in, tid);
            gmac8(acc, h0,  ws + OFF_WPK + 1L * 1048576L, r0, jl, bg, sm.g.in, tid);
            cell8(acc, r0, tid,
                  ws + OFF_C + ((long)so * 3 + 0) * 32768 + (long)bh * 32 * HD,
                  ws + OFF_C + ((long)sn * 3 + 0) * 32768 + (long)bh * 32 * HD,
                  ws + OFF_H + ((long)sn * 3 + 0) * 32768 + (long)bh * 32 * HD, sm.g.g);
        } else {
            int u = bx - 512;
            int px = u >> 1, bh = u & 1, r0 = px * 8;
            int jl = tid & 7, bg = tid >> 3;
            {
                float acc = ws[OFF_BIAS + 2048 + r0 + jl];
                const float* h1 = ws + OFF_H + ((long)so * 3 + 1) * 32768 + (long)bh * 32 * HD;
                gmac8(acc, h1, ws + OFF_WPK + 3L * 1048576L, r0, jl, bg, sm.g.in, tid);
                ws[OFF_P1 + (long)(bh * 32 + bg) * G4 + r0 + jl] = acc;
            }
            {
                float acc = ws[OFF_BIAS + 4096 + r0 + jl];
                const float* h2 = ws + OFF_H + ((long)so * 3 + 2) * 32768 + (long)bh * 32 * HD;
                gmac8(acc, h2, ws + OFF_WPK + 5L * 1048576L, r0, jl, bg, sm.g.in, tid);
                ws[OFF_P2 + (long)(bh * 32 + bg) * G4 + r0 + jl] = acc;
            }
        }
        gbar(wsbar, bx, ++bc);

        // ---- PHASE B: LSTM layer 1 ----
        if (bx < 512) {
            int px = bx >> 1, bh = bx & 1, r0 = px * 8;
            int jl = tid & 7, bg = tid >> 3;
            float acc = ws[OFF_P1 + (long)(bh * 32 + bg) * G4 + r0 + jl];
            const float* h0n = ws + OFF_H + ((long)sn * 3 + 0) * 32768 + (long)bh * 32 * HD;
            gmac8(acc, h0n, ws + OFF_WPK + 2L * 1048576L, r0, jl, bg, sm.g.in, tid);
            cell8(acc, r0, tid,
                  ws + OFF_C + ((long)so * 3 + 1) * 32768 + (long)bh * 32 * HD,
                  ws + OFF_C + ((long)sn * 3 + 1) * 32768 + (long)bh * 32 * HD,
                  ws + OFF_H + ((long)sn * 3 + 1) * 32768 + (long)bh * 32 * HD, sm.g.g);
        }
        gbar(wsbar, bx, ++bc);

        // ---- PHASE C: LSTM layer 2 ----
        if (bx < 512) {
            int px = bx >> 1, bh = bx & 1, r0 = px * 8;
            int jl = tid & 7, bg = tid >> 3;
            float acc = ws[OFF_P2 + (long)(bh * 32 + bg) * G4 + r0 + jl];
            const float* h1n = ws + OFF_H + ((long)sn * 3 + 1) * 32768 + (long)bh * 32 * HD;
            gmac8(acc, h1n, ws + OFF_WPK + 4L * 1048576L, r0, jl, bg, sm.g.in, tid);
            cell8(acc, r0, tid,
                  ws + OFF_C + ((long)so * 3 + 2) * 32768 + (long)bh * 32 * HD,
                  ws + OFF_C + ((long)sn * 3 + 2) * 32768 + (long)bh * 32 * HD,
                  ws + OFF_H + ((long)sn * 3 + 2) * 32768 + (long)bh * 32 * HD, sm.g.g);
        }
        gbar(wsbar, bx, ++bc);

        // ---- PHASE D: query = h2 @ Wfc^T + b_fc (256 units: b x kq) ----
        if (bx < 256) {
            int b = bx >> 2, kq = bx & 3;
            const float* h2p = ws + OFF_H + ((long)sn * 3 + 2) * 32768 + (long)b * HD;
            sm.q.h2[tid] = h2p[tid];
            sm.q.h2[tid + 256] = h2p[tid + 256];
            __syncthreads();
            int o = tid & 63, kh = tid >> 6;
            float acc = 0.f;
            const float* Wf = ws + OFF_WFC;
            #pragma unroll 4
            for (int k4i = 0; k4i < 32; ++k4i) {
                int k4 = kh * 32 + k4i;
                float4 wv = *reinterpret_cast<const float4*>(Wf + ((long)k4 * 256 + kq * 64 + o) * 4);
                float4 x  = *reinterpret_cast<const float4*>(&sm.q.h2[k4 * 4]);
                acc += x.x * wv.x + x.y * wv.y + x.z * wv.z + x.w * wv.w;
            }
            sm.q.qp[kh][o] = acc;
            __syncthreads();
            if (tid < 64) {
                float q = sm.q.qp[0][tid] + sm.q.qp[1][tid] + sm.q.qp[2][tid] + sm.q.qp[3][tid]
                          + b_fc[kq * 64 + tid];
                ws[OFF_QUERY + (long)b * 256 + kq * 64 + tid] = q;
            }
        }
        gbar(wsbar, bx, ++bc);

        // ---- PHASE E: attention single pass (1024 units: b x 16 chunks of 64 l) ----
        {
            int b = bx >> 4, ch = bx & 15, l0 = ch * 64;
            int lane = tid & 63, w = tid >> 6;
            int j = lane & 15, rq = lane >> 4;
            float4 q4[4];
            #pragma unroll
            for (int kk = 0; kk < 4; ++kk)
                q4[kk] = *reinterpret_cast<const float4*>(ws + OFF_QUERY + (long)b * 256 + kk * 64 + j * 4);
            int n = fsl[b];
            for (int qq = 0; qq < 4; ++qq) {
                int l = l0 + w * 16 + qq * 4 + rq;
                const float* Kr = enc_key + ((long)(b * LQ + l)) * KVD;
                float s = 0.f;
                #pragma unroll
                for (int kk = 0; kk < 4; ++kk) {
                    float4 kv = *reinterpret_cast<const float4*>(Kr + kk * 64 + j * 4);
                    s += kv.x * q4[kk].x + kv.y * q4[kk].y + kv.z * q4[kk].z + kv.w * q4[kk].w;
                }
                s += __shfl_xor(s, 1, 64); s += __shfl_xor(s, 2, 64);
                s += __shfl_xor(s, 4, 64); s += __shfl_xor(s, 8, 64);
                float e = (l < n) ? s : 0.f;   // softmax(energy*mask): masked -> exp(0)
                if (j == 0) sm.a.eL[w * 16 + qq * 4 + rq] = e;
            }
            __syncthreads();
            if (w == 0) {
                float e = sm.a.eL[lane];
                float m = e;
                m = fmaxf(m, __shfl_xor(m, 1, 64));  m = fmaxf(m, __shfl_xor(m, 2, 64));
                m = fmaxf(m, __shfl_xor(m, 4, 64));  m = fmaxf(m, __shfl_xor(m, 8, 64));
                m = fmaxf(m, __shfl_xor(m, 16, 64)); m = fmaxf(m, __shfl_xor(m, 32, 64));
                float p = expf(e - m);
                sm.a.pL[lane] = p;
                float su = p;
                su += __shfl_xor(su, 1, 64);  su += __shfl_xor(su, 2, 64);
                su += __shfl_xor(su, 4, 64);  su += __shfl_xor(su, 8, 64);
                su += __shfl_xor(su, 16, 64); su += __shfl_xor(su, 32, 64);
                if (attDirect) attp[((long)(b * LQ + l0 + lane)) * TT + t] = p;
                else           attp[(long)t * 65536 + b * LQ + l0 + lane] = p;
                if (lane == 0) {
                    ws[OFF_STATS + ((long)(b * 16 + ch)) * 2 + 0] = m;
                    ws[OFF_STATS + ((long)(b * 16 + ch)) * 2 + 1] = su;
                }
            }
            __syncthreads();
            float acc = 0.f;
            const float* Vb = enc_value + ((long)(b * LQ + l0)) * KVD + tid;
            #pragma unroll 8
            for (int i = 0; i < 64; ++i) acc += sm.a.pL[i] * Vb[(long)i * KVD];
            ws[OFF_CTXP + ((long)(b * 16 + ch)) * 256 + tid] = acc;
        }
        gbar(wsbar, bx, ++bc);

        // ---- PHASE F: combine + MLP + gumbel + argmax + emb (64 units) ----
        if (bx < 64) {
            int b = bx;
            const float* st = ws + OFF_STATS + (long)b * 32;
            if (tid == 0) {
                float M = -3.4e38f;
                for (int i = 0; i < 16; ++i) M = fmaxf(M, st[i * 2]);
                float S = 0.f;
                for (int i = 0; i < 16; ++i) S += st[i * 2 + 1] * expf(st[i * 2] - M);
                float iS = 1.f / S;
                for (int i = 0; i < 16; ++i) sm.f.sc[i] = expf(st[i * 2] - M) * iS;
            }
            __syncthreads();
            if (tid < 16) ws[OFF_SCALES + ((long)t * 64 + b) * 16 + tid] = sm.f.sc[tid];
            float ctx = 0.f;
            #pragma unroll
            for (int i = 0; i < 16; ++i)
                ctx += sm.f.sc[i] * ws[OFF_CTXP + ((long)(b * 16 + i)) * 256 + tid];
            sm.f.cat[256 + tid] = ctx;
            sm.f.cat[tid] = ws[OFF_QUERY + (long)b * 256 + tid];
            ws[OFF_RNN + (long)sn * 32768 + (long)b * HD + 256 + tid] = ctx;
            __syncthreads();
            float a0 = b_mlp1[tid], a1 = b_mlp1[tid + 256];
            const float* Wm1 = ws + OFF_WM1;
            #pragma unroll 2
            for (int k4 = 0; k4 < 128; ++k4) {
                float4 x  = *reinterpret_cast<const float4*>(&sm.f.cat[k4 * 4]);
                float4 wA = *reinterpret_cast<const float4*>(Wm1 + ((long)k4 * 512 + tid) * 4);
                float4 wB = *reinterpret_cast<const float4*>(Wm1 + ((long)k4 * 512 + tid + 256) * 4);
                a0 += x.x * wA.x + x.y * wA.y + x.z * wA.z + x.w * wA.w;
                a1 += x.x * wB.x + x.y * wB.y + x.z * wB.z + x.w * wB.w;
            }
            sm.f.hm[tid]       = (a0 >= 0.f) ? a0 : 0.9f * a0;
            sm.f.hm[tid + 256] = (a1 >= 0.f) ? a1 : 0.9f * a1;
            __syncthreads();
            int w = tid >> 6, lane = tid & 63;
            if (lane < VV) {
                float acc = 0.f;
                const float* W2 = ws + OFF_WM2T;
                for (int m = w * 128; m < w * 128 + 128; ++m) acc += sm.f.hm[m] * W2[(long)m * VV + lane];
                sm.f.yp[w][lane] = acc;
            }
            __syncthreads();
            if (tid < VV) {
                float y = sm.f.yp[0][tid] + sm.f.yp[1][tid] + sm.f.yp[2][tid] + sm.f.yp[3][tid] + b_mlp2[tid];
                out[OUT_Y + ((long)b * TT + t) * VV + tid] = y;
                float u = gumbel_u[((long)t * BB + b) * VV + tid];
                float g = -logf(-logf(u + 1e-10f) + 1e-10f);
                sm.f.sv[tid] = y + g;
            }
            __syncthreads();
            if (tid == 0) {
                float mx = sm.f.sv[0]; int am = 0;
                for (int v = 1; v < VV; ++v) if (sm.f.sv[v] > mx) { mx = sm.f.sv[v]; am = v; }
                float Z = 0.f;
                for (int v = 0; v < VV; ++v) { float p = expf(sm.f.sv[v] - mx); sm.f.ysm[v] = p; Z += p; }
                float iz = 1.f / Z;
                for (int v = 0; v < VV; ++v) sm.f.ysm[v] *= iz;
                out[OUT_LBL + (long)b * TT + t] = (float)am;
            }
            __syncthreads();
            float acc = b_emb[tid];
            const float* We = ws + OFF_WEMBT;
            #pragma unroll
            for (int v = 0; v < VV; ++v) acc += sm.f.ysm[v] * We[(long)v * 256 + tid];
            ws[OFF_RNN + (long)sn * 32768 + (long)b * HD + tid] = acc;
        }
        gbar(wsbar, bx, ++bc);
    }
}

// ---------------- epilogues ----------------
__global__ __launch_bounds__(256) void k_labels(const int* __restrict__ lp, float* __restrict__ out)
{
    int id = blockIdx.x * 256 + threadIdx.x;
    if (id < BB * TT) {
        int b = id / TT, t = id % TT;
        out[OUT_LPT + id] = (float)lp[(long)t * BB + b];
    }
}

// full path: normalize (p * scale) + transpose [t][b*1024+l] -> out [b][l][t]
__global__ __launch_bounds__(256) void k_att_fin(const float* __restrict__ ws_ro,
                                                 float* __restrict__ out)
{
    __shared__ float tile[32][33];
    int blt = blockIdx.x, ttb = blockIdx.y;
    int tx = threadIdx.x & 31, ty = threadIdx.x >> 5;
    int bl0 = blt * 32, t0 = ttb * 32;
    int b = bl0 >> 10, ch = (bl0 & 1023) >> 6;
    #pragma unroll
    for (int jj = 0; jj < 4; ++jj) {
        int trow = t0 + ty + jj * 8;
        if (trow < TT) {
            float s = ws_ro[OFF_SCALES + ((long)trow * 64 + b) * 16 + ch];
            tile[ty + jj * 8][tx] = ws_ro[OFF_ATT + (long)trow * 65536 + bl0 + tx] * s;
        }
    }
    __syncthreads();
    #pragma unroll
    for (int jj = 0; jj < 4; ++jj) {
        int row = bl0 + ty + jj * 8;
        int col = t0 + tx;
        if (col < TT) out[OUT_ATT + (long)row * TT + col] = tile[tx][ty + jj * 8];
    }
}

// direct path: in-place scale of out[b][l][t]
__global__ __launch_bounds__(320) void k_att_scale(const float* __restrict__ ws_ro,
                                                    float* __restrict__ out)
{
    int bl = blockIdx.x;  // b*1024 + l
    int b = bl >> 10, ch = (bl & 1023) >> 6;
    int tid = threadIdx.x;
    if (tid < TT) {
        long base = OUT_ATT + (long)bl * TT;
        out[base + tid] *= ws_ro[OFF_SCALES + ((long)tid * 64 + b) * 16 + ch];
    }
}

extern "C" void kernel_launch(void* const* d_in, const int* in_sizes, int n_in,
                              void* d_out, int out_size, void* d_ws, size_t ws_size,
                              hipStream_t stream)
{
    const float* enc_key   = (const float*)d_in[0];
    const float* enc_value = (const float*)d_in[1];
    const int*   labels    = (const int*)d_in[2];
    const int*   fsl       = (const int*)d_in[3];
    const float* gumbel_u  = (const float*)d_in[4];
    const float* W_emb     = (const float*)d_in[5];
    const float* b_emb     = (const float*)d_in[6];
    const float* W_fc      = (const float*)d_in[7];
    const float* b_fc      = (const float*)d_in[8];
    const float* W_mlp1    = (const float*)d_in[9];
    const float* b_mlp1    = (const float*)d_in[10];
    const float* W_mlp2    = (const float*)d_in[11];
    const float* b_mlp2    = (const float*)d_in[12];
    const float* Wih0 = (const float*)d_in[13];
    const float* Whh0 = (const float*)d_in[14];
    const float* bih0 = (const float*)d_in[15];
    const float* bhh0 = (const float*)d_in[16];
    const float* Wih1 = (const float*)d_in[17];
    const float* Whh1 = (const float*)d_in[18];
    const float* bih1 = (const float*)d_in[19];
    const float* bhh1 = (const float*)d_in[20];
    const float* Wih2 = (const float*)d_in[21];
    const float* Whh2 = (const float*)d_in[22];
    const float* bih2 = (const float*)d_in[23];
    const float* bhh2 = (const float*)d_in[24];
    float* ws  = (float*)d_ws;
    float* out = (float*)d_out;

    const bool full = ws_size >= (size_t)WS_FLOATS_FULL * 4;
    float* attp = full ? (ws + OFF_ATT) : (out + OUT_ATT);
    const int attDirect = full ? 0 : 1;

    hipMemsetAsync((char*)d_ws + OFF_BAR * 4, 0, 4224 * 4, stream);
    hipLaunchKernelGGL(k_pack_gates, dim3(6168), dim3(256), 0, stream,
                       Wih0, Whh0, Wih1, Whh1, Wih2, Whh2,
                       bih0, bhh0, bih1, bhh1, bih2, bhh2, ws);
    hipLaunchKernelGGL(k_pack_small, dim3(483), dim3(256), 0, stream,
                       W_fc, W_mlp1, W_mlp2, W_emb, ws);
    hipLaunchKernelGGL(k_init, dim3(512), dim3(256), 0, stream, W_emb, b_emb, ws);

    hipLaunchKernelGGL(k_loop, dim3(NBLK), dim3(256), 0, stream,
                       enc_key, enc_value, fsl, gumbel_u, b_fc, b_mlp1, b_mlp2, b_emb,
                       ws, out, attp, attDirect);

    hipLaunchKernelGGL(k_labels, dim3(75), dim3(256), 0, stream, labels, out);
    if (full) hipLaunchKernelGGL(k_att_fin, dim3(2048, 10), dim3(256), 0, stream, ws, out);
    else      hipLaunchKernelGGL(k_att_scale, dim3(65536), dim3(320), 0, stream, ws, out);
}

// Round 4
// 92644.171 us; speedup vs baseline: 2.3599x; 1.6292x over previous
//
#include <hip/hip_runtime.h>
#include <math.h>

#define BB 64
#define LQ 1024
#define KVD 256
#define HD 512
#define ED 256
#define TT 300
#define VV 33
#define MHD 512
#define G4 2048
#define NBLK 1024
#define NGRP 32
#define GSZ 32

// ws float offsets
#define OFF_WPK     0L            // 6 x [128 k4][2048 r][4] packed gate weights
#define OFF_BIAS    6291456L      // 3*2048 combined bih+bhh, row r = m*4+g
#define OFF_WFC     6297600L      // [128 k4][256 kv][4]
#define OFF_WM1     6428672L      // [128 k4][512 m][4]
#define OFF_WM2T    6690816L      // [512][33]
#define OFF_WEMBT   6707712L      // [33][256]
#define OFF_H       6716160L      // [2 slot][3 layer][64][512]   (coherent)
#define OFF_C       6912768L      // block-private (cached)
#define OFF_RNN     7109376L      // [2 slot][64][512]            (coherent)
#define OFF_P1      7174912L      // [64][2048]                   (coherent)
#define OFF_P2      7305984L
#define OFF_QUERY   7437056L      // [64][256]                    (coherent)
#define OFF_STATS   7453440L      // [64][16][2]                  (coherent)
#define OFF_CTXP    7455488L      // [64][16][256]                (coherent)
#define OFF_SCALES  7717632L      // [300][64][16]
#define OFF_BAR     8024832L      // tree barrier: 4224 floats
#define OFF_ATT     8029056L      // [300][64][1024] unnormalized p
#define WS_FLOATS_FULL 27689856L

// out float offsets
#define OUT_Y      0L
#define OUT_LBL    633600L
#define OUT_LPT    652800L
#define OUT_ATT    672000L

// ---------------- MALL-coherent access helpers (bypass L1/L2) ----------------
__device__ __forceinline__ float ldc(const float* p) {
    unsigned u = __hip_atomic_load((const unsigned*)p, __ATOMIC_RELAXED, __HIP_MEMORY_SCOPE_AGENT);
    union { unsigned u; float f; } c; c.u = u; return c.f;
}
__device__ __forceinline__ void stc(float* p, float v) {
    union { float f; unsigned u; } c; c.f = v;
    __hip_atomic_store((unsigned*)p, c.u, __ATOMIC_RELAXED, __HIP_MEMORY_SCOPE_AGENT);
}
__device__ __forceinline__ float2 ldc2(const float* p) {
    unsigned long long u = __hip_atomic_load((const unsigned long long*)p,
                                             __ATOMIC_RELAXED, __HIP_MEMORY_SCOPE_AGENT);
    union { unsigned long long u; float2 f; } c; c.u = u; return c.f;
}

// ---------------- packing (once per call) ----------------
__global__ __launch_bounds__(256) void k_pack_gates(
    const float* __restrict__ Wih0, const float* __restrict__ Whh0,
    const float* __restrict__ Wih1, const float* __restrict__ Whh1,
    const float* __restrict__ Wih2, const float* __restrict__ Whh2,
    const float* __restrict__ bih0, const float* __restrict__ bhh0,
    const float* __restrict__ bih1, const float* __restrict__ bhh1,
    const float* __restrict__ bih2, const float* __restrict__ bhh2,
    float* __restrict__ ws)
{
    long id = (long)blockIdx.x * 256 + threadIdx.x;
    if (id < 6L * 262144L) {
        int mat = (int)(id / 262144L);
        int rem = (int)(id % 262144L);
        int k4 = rem >> 11;
        int r  = rem & 2047;
        int m = r >> 2, g = r & 3;
        int row = g * HD + m;
        const float* W = (mat==0)?Wih0:(mat==1)?Whh0:(mat==2)?Wih1:(mat==3)?Whh1:(mat==4)?Wih2:Whh2;
        const float4 v = *reinterpret_cast<const float4*>(W + (long)row * HD + k4 * 4);
        *reinterpret_cast<float4*>(ws + OFF_WPK + ((long)mat * 262144L + rem) * 4) = v;
    } else {
        long bid = id - 6L * 262144L;
        if (bid < 3L * 2048L) {
            int l = (int)(bid / 2048), r = (int)(bid % 2048);
            int m = r >> 2, g = r & 3;
            int row = g * HD + m;
            const float* bi = (l==0)?bih0:(l==1)?bih1:bih2;
            const float* bh = (l==0)?bhh0:(l==1)?bhh1:bhh2;
            ws[OFF_BIAS + bid] = bi[row] + bh[row];
        }
    }
}

__global__ __launch_bounds__(256) void k_pack_small(
    const float* __restrict__ W_fc, const float* __restrict__ W_mlp1,
    const float* __restrict__ W_mlp2, const float* __restrict__ W_emb,
    float* __restrict__ ws)
{
    int id = blockIdx.x * 256 + threadIdx.x;
    if (id < 32768) {
        int k4 = id >> 8, kv = id & 255;
        const float4 v = *reinterpret_cast<const float4*>(W_fc + (long)kv * HD + k4 * 4);
        *reinterpret_cast<float4*>(ws + OFF_WFC + (long)id * 4) = v;
        return;
    }
    id -= 32768;
    if (id < 65536) {
        int k4 = id >> 9, m = id & 511;
        const float4 v = *reinterpret_cast<const float4*>(W_mlp1 + (long)m * HD + k4 * 4);
        *reinterpret_cast<float4*>(ws + OFF_WM1 + (long)id * 4) = v;
        return;
    }
    id -= 65536;
    if (id < 512 * VV) {
        int m = id / VV, v = id % VV;
        ws[OFF_WM2T + id] = W_mlp2[(long)v * MHD + m];
        return;
    }
    id -= 512 * VV;
    if (id < VV * 256) {
        int v = id >> 8, e = id & 255;
        ws[OFF_WEMBT + id] = W_emb[(long)e * VV + v];
    }
}

__global__ __launch_bounds__(256) void k_init(
    const float* __restrict__ W_emb, const float* __restrict__ b_emb, float* __restrict__ ws)
{
    int id = blockIdx.x * 256 + threadIdx.x;
    if (id < 98304) { ws[OFF_H + id] = 0.f; ws[OFF_C + id] = 0.f; return; }
    id -= 98304;
    if (id < BB * HD) {
        int k = id & 511;
        float v = 0.f;
        if (k < ED) v = W_emb[(long)k * VV + 0] + b_emb[k];
        ws[OFF_RNN + id] = v;
    }
}

// ---------------- persistent loop kernel ----------------
struct SMGates { float in[32][132]; float g[8][33]; };
struct SMQuery { float h2[512]; float qp[4][64]; };
struct SMAttn  { float eL[64]; float pL[64]; };
struct SMFin   { float cat[512]; float hm[512]; float yp[4][33]; float sv[33];
                 float ysm[33]; float sc[16]; float st[32]; };
union SMU { SMGates g; SMQuery q; SMAttn a; SMFin f; };

// Fence-free tree barrier: all cross-block data moves via sc0/sc1 (MALL)
// accesses, so no L2 writeback/invalidate is needed. Each wave drains its
// outstanding coherent stores (vmcnt), then pure relaxed counter sync.
__device__ __forceinline__ void gbar(float* wsbar, int bx, unsigned bc)
{
    asm volatile("s_waitcnt vmcnt(0)" ::: "memory");
    __syncthreads();
    if (threadIdx.x == 0) {
        unsigned* rootCnt = (unsigned*)(wsbar);
        unsigned* rootGo  = (unsigned*)(wsbar + 64);
        int g = bx & (NGRP - 1);
        unsigned* grpCnt = (unsigned*)(wsbar + 128 + (long)g * 64);
        unsigned* grpGo  = (unsigned*)(wsbar + 128 + (long)NGRP * 64 + (long)g * 64);
        unsigned old = __hip_atomic_fetch_add(grpCnt, 1u, __ATOMIC_RELAXED, __HIP_MEMORY_SCOPE_AGENT);
        if (old == GSZ * bc - 1) {
            unsigned ro = __hip_atomic_fetch_add(rootCnt, 1u, __ATOMIC_RELAXED, __HIP_MEMORY_SCOPE_AGENT);
            if (ro == NGRP * bc - 1) {
                __hip_atomic_store(rootGo, bc, __ATOMIC_RELAXED, __HIP_MEMORY_SCOPE_AGENT);
            } else {
                while (__hip_atomic_load(rootGo, __ATOMIC_RELAXED, __HIP_MEMORY_SCOPE_AGENT) < bc)
                    __builtin_amdgcn_s_sleep(1);
            }
            __hip_atomic_store(grpGo, bc, __ATOMIC_RELAXED, __HIP_MEMORY_SCOPE_AGENT);
        } else {
            while (__hip_atomic_load(grpGo, __ATOMIC_RELAXED, __HIP_MEMORY_SCOPE_AGENT) < bc)
                __builtin_amdgcn_s_sleep(1);
        }
    }
    __syncthreads();
}

// 8 rows x 32 batch tile MAC with coherent, pipelined staging.
// acc += (inp[32b x 512k] @ Wpk rows r0..r0+7); inp read via MALL (sc1).
__device__ __forceinline__ void gmac8(float& acc, const float* inp, const float* Wpk,
                                      int r0, int jl, int bg, float (*lin)[132], int tid)
{
    float2 pre[8];
    #pragma unroll
    for (int i = 0; i < 8; ++i) {
        int fid = tid + i * 256;
        pre[i] = ldc2(inp + (long)(fid >> 6) * HD + (fid & 63) * 2);
    }
    for (int kc = 0; kc < 4; ++kc) {
        __syncthreads();
        #pragma unroll
        for (int i = 0; i < 8; ++i) {
            int fid = tid + i * 256;
            *reinterpret_cast<float2*>(&lin[fid >> 6][(fid & 63) * 2]) = pre[i];
        }
        __syncthreads();
        if (kc < 3) {
            #pragma unroll
            for (int i = 0; i < 8; ++i) {
                int fid = tid + i * 256;
                pre[i] = ldc2(inp + (long)(fid >> 6) * HD + (kc + 1) * 128 + (fid & 63) * 2);
            }
        }
        const float* Wb = Wpk + ((long)(kc * 32) * G4 + (r0 + jl)) * 4;
        #pragma unroll 4
        for (int k4 = 0; k4 < 32; ++k4) {
            float4 w = *reinterpret_cast<const float4*>(Wb + (long)k4 * G4 * 4);
            float4 x = *reinterpret_cast<const float4*>(&lin[bg][k4 * 4]);
            acc += x.x * w.x + x.y * w.y + x.z * w.z + x.w * w.w;
        }
    }
}

__device__ __forceinline__ void cell8(float acc, int r0, int tid,
    const float* c_old, float* c_new, float* h_new, float (*g)[33])
{
    g[tid & 7][tid >> 3] = acc;
    __syncthreads();
    if (tid < 64) {
        int ml = tid >> 5, bl = tid & 31;
        int m = (r0 >> 2) + ml;
        float gi = g[ml * 4 + 0][bl];
        float gf = g[ml * 4 + 1][bl];
        float gg = g[ml * 4 + 2][bl];
        float go = g[ml * 4 + 3][bl];
        float si = 1.f / (1.f + expf(-gi));
        float sf = 1.f / (1.f + expf(-gf));
        float tg = tanhf(gg);
        float so = 1.f / (1.f + expf(-go));
        float c2 = sf * c_old[(long)bl * HD + m] + si * tg;   // c: block-private, cached
        c_new[(long)bl * HD + m] = c2;
        stc(h_new + (long)bl * HD + m, so * tanhf(c2));       // h: shared, coherent
    }
    __syncthreads();
}

__global__ __launch_bounds__(256, 4) void k_loop(
    const float* __restrict__ enc_key, const float* __restrict__ enc_value,
    const int* __restrict__ fsl, const float* __restrict__ gumbel_u,
    const float* __restrict__ b_fc, const float* __restrict__ b_mlp1,
    const float* __restrict__ b_mlp2, const float* __restrict__ b_emb,
    float* ws, float* out, float* attp, int attDirect)
{
    __shared__ SMU sm;
    int bx = blockIdx.x, tid = threadIdx.x;
    float* wsbar = ws + OFF_BAR;
    unsigned bc = 0;

    for (int t = 0; t < TT; ++t) {
        int so = t & 1, sn = so ^ 1;

        // ---- PHASE A: L0 full gates + Whh partials L1,L2 ----
        if (bx < 512) {
            int px = bx >> 1, bh = bx & 1, r0 = px * 8;
            int jl = tid & 7, bg = tid >> 3;
            float acc = ws[OFF_BIAS + r0 + jl];
            const float* rnn = ws + OFF_RNN + (long)so * 32768 + (long)bh * 32 * HD;
            const float* h0  = ws + OFF_H + ((long)so * 3 + 0) * 32768 + (long)bh * 32 * HD;
            gmac8(acc, rnn, ws + OFF_WPK + 0L * 1048576L, r0, jl, bg, sm.g.in, tid);
            gmac8(acc, h0,  ws + OFF_WPK + 1L * 1048576L, r0, jl, bg, sm.g.in, tid);
            cell8(acc, r0, tid,
                  ws + OFF_C + ((long)so * 3 + 0) * 32768 + (long)bh * 32 * HD,
                  ws + OFF_C + ((long)sn * 3 + 0) * 32768 + (long)bh * 32 * HD,
                  ws + OFF_H + ((long)sn * 3 + 0) * 32768 + (long)bh * 32 * HD, sm.g.g);
        } else {
            int u = bx - 512;
            int px = u >> 1, bh = u & 1, r0 = px * 8;
            int jl = tid & 7, bg = tid >> 3;
            {
                float acc = ws[OFF_BIAS + 2048 + r0 + jl];
                const float* h1 = ws + OFF_H + ((long)so * 3 + 1) * 32768 + (long)bh * 32 * HD;
                gmac8(acc, h1, ws + OFF_WPK + 3L * 1048576L, r0, jl, bg, sm.g.in, tid);
                stc(ws + OFF_P1 + (long)(bh * 32 + bg) * G4 + r0 + jl, acc);
            }
            {
                float acc = ws[OFF_BIAS + 4096 + r0 + jl];
                const float* h2 = ws + OFF_H + ((long)so * 3 + 2) * 32768 + (long)bh * 32 * HD;
                gmac8(acc, h2, ws + OFF_WPK + 5L * 1048576L, r0, jl, bg, sm.g.in, tid);
                stc(ws + OFF_P2 + (long)(bh * 32 + bg) * G4 + r0 + jl, acc);
            }
        }
        gbar(wsbar, bx, ++bc);

        // ---- PHASE B: LSTM layer 1 ----
        if (bx < 512) {
            int px = bx >> 1, bh = bx & 1, r0 = px * 8;
            int jl = tid & 7, bg = tid >> 3;
            float acc = ldc(ws + OFF_P1 + (long)(bh * 32 + bg) * G4 + r0 + jl);
            const float* h0n = ws + OFF_H + ((long)sn * 3 + 0) * 32768 + (long)bh * 32 * HD;
            gmac8(acc, h0n, ws + OFF_WPK + 2L * 1048576L, r0, jl, bg, sm.g.in, tid);
            cell8(acc, r0, tid,
                  ws + OFF_C + ((long)so * 3 + 1) * 32768 + (long)bh * 32 * HD,
                  ws + OFF_C + ((long)sn * 3 + 1) * 32768 + (long)bh * 32 * HD,
                  ws + OFF_H + ((long)sn * 3 + 1) * 32768 + (long)bh * 32 * HD, sm.g.g);
        }
        gbar(wsbar, bx, ++bc);

        // ---- PHASE C: LSTM layer 2 ----
        if (bx < 512) {
            int px = bx >> 1, bh = bx & 1, r0 = px * 8;
            int jl = tid & 7, bg = tid >> 3;
            float acc = ldc(ws + OFF_P2 + (long)(bh * 32 + bg) * G4 + r0 + jl);
            const float* h1n = ws + OFF_H + ((long)sn * 3 + 1) * 32768 + (long)bh * 32 * HD;
            gmac8(acc, h1n, ws + OFF_WPK + 4L * 1048576L, r0, jl, bg, sm.g.in, tid);
            cell8(acc, r0, tid,
                  ws + OFF_C + ((long)so * 3 + 2) * 32768 + (long)bh * 32 * HD,
                  ws + OFF_C + ((long)sn * 3 + 2) * 32768 + (long)bh * 32 * HD,
                  ws + OFF_H + ((long)sn * 3 + 2) * 32768 + (long)bh * 32 * HD, sm.g.g);
        }
        gbar(wsbar, bx, ++bc);

        // ---- PHASE D: query = h2 @ Wfc^T + b_fc (256 blocks: b x kq) ----
        if (bx < 256) {
            int b = bx >> 2, kq = bx & 3;
            const float* h2p = ws + OFF_H + ((long)sn * 3 + 2) * 32768 + (long)b * HD;
            { float2 v = ldc2(h2p + tid * 2); *reinterpret_cast<float2*>(&sm.q.h2[tid * 2]) = v; }
            __syncthreads();
            int o = tid & 63, kh = tid >> 6;
            float acc = 0.f;
            const float* Wf = ws + OFF_WFC;
            #pragma unroll 4
            for (int k4i = 0; k4i < 32; ++k4i) {
                int k4 = kh * 32 + k4i;
                float4 wv = *reinterpret_cast<const float4*>(Wf + ((long)k4 * 256 + kq * 64 + o) * 4);
                float4 x  = *reinterpret_cast<const float4*>(&sm.q.h2[k4 * 4]);
                acc += x.x * wv.x + x.y * wv.y + x.z * wv.z + x.w * wv.w;
            }
            sm.q.qp[kh][o] = acc;
            __syncthreads();
            if (tid < 64) {
                float q = sm.q.qp[0][tid] + sm.q.qp[1][tid] + sm.q.qp[2][tid] + sm.q.qp[3][tid]
                          + b_fc[kq * 64 + tid];
                stc(ws + OFF_QUERY + (long)b * 256 + kq * 64 + tid, q);
            }
        }
        gbar(wsbar, bx, ++bc);

        // ---- PHASE E: attention single pass (1024 blocks: b x 16 chunks of 64 l) ----
        {
            int b = bx >> 4, ch = bx & 15, l0 = ch * 64;
            int lane = tid & 63, w = tid >> 6;
            int j = lane & 15, rq = lane >> 4;
            const float* qb = ws + OFF_QUERY + (long)b * 256;
            float4 q4[4];
            #pragma unroll
            for (int kk = 0; kk < 4; ++kk) {
                float2 a = ldc2(qb + kk * 64 + j * 4);
                float2 bq = ldc2(qb + kk * 64 + j * 4 + 2);
                q4[kk] = make_float4(a.x, a.y, bq.x, bq.y);
            }
            int n = fsl[b];
            for (int qq = 0; qq < 4; ++qq) {
                int l = l0 + w * 16 + qq * 4 + rq;
                const float* Kr = enc_key + ((long)(b * LQ + l)) * KVD;
                float s = 0.f;
                #pragma unroll
                for (int kk = 0; kk < 4; ++kk) {
                    float4 kv = *reinterpret_cast<const float4*>(Kr + kk * 64 + j * 4);
                    s += kv.x * q4[kk].x + kv.y * q4[kk].y + kv.z * q4[kk].z + kv.w * q4[kk].w;
                }
                s += __shfl_xor(s, 1, 64); s += __shfl_xor(s, 2, 64);
                s += __shfl_xor(s, 4, 64); s += __shfl_xor(s, 8, 64);
                float e = (l < n) ? s : 0.f;   // softmax(energy*mask): masked -> exp(0)
                if (j == 0) sm.a.eL[w * 16 + qq * 4 + rq] = e;
            }
            __syncthreads();
            if (w == 0) {
                float e = sm.a.eL[lane];
                float m = e;
                m = fmaxf(m, __shfl_xor(m, 1, 64));  m = fmaxf(m, __shfl_xor(m, 2, 64));
                m = fmaxf(m, __shfl_xor(m, 4, 64));  m = fmaxf(m, __shfl_xor(m, 8, 64));
                m = fmaxf(m, __shfl_xor(m, 16, 64)); m = fmaxf(m, __shfl_xor(m, 32, 64));
                float p = expf(e - m);
                sm.a.pL[lane] = p;
                float su = p;
                su += __shfl_xor(su, 1, 64);  su += __shfl_xor(su, 2, 64);
                su += __shfl_xor(su, 4, 64);  su += __shfl_xor(su, 8, 64);
                su += __shfl_xor(su, 16, 64); su += __shfl_xor(su, 32, 64);
                if (attDirect) attp[((long)(b * LQ + l0 + lane)) * TT + t] = p;
                else           attp[(long)t * 65536 + b * LQ + l0 + lane] = p;
                if (lane == 0) {
                    stc(ws + OFF_STATS + ((long)(b * 16 + ch)) * 2 + 0, m);
                    stc(ws + OFF_STATS + ((long)(b * 16 + ch)) * 2 + 1, su);
                }
            }
            __syncthreads();
            float acc = 0.f;
            const float* Vb = enc_value + ((long)(b * LQ + l0)) * KVD + tid;
            #pragma unroll 8
            for (int i = 0; i < 64; ++i) acc += sm.a.pL[i] * Vb[(long)i * KVD];
            stc(ws + OFF_CTXP + ((long)(b * 16 + ch)) * 256 + tid, acc);
        }
        gbar(wsbar, bx, ++bc);

        // ---- PHASE F: combine + MLP + gumbel + argmax + emb (64 blocks) ----
        if (bx < 64) {
            int b = bx;
            if (tid < 32) sm.f.st[tid] = ldc(ws + OFF_STATS + (long)b * 32 + tid);
            __syncthreads();
            if (tid == 0) {
                float M = -3.4e38f;
                for (int i = 0; i < 16; ++i) M = fmaxf(M, sm.f.st[i * 2]);
                float S = 0.f;
                for (int i = 0; i < 16; ++i) S += sm.f.st[i * 2 + 1] * expf(sm.f.st[i * 2] - M);
                float iS = 1.f / S;
                for (int i = 0; i < 16; ++i) sm.f.sc[i] = expf(sm.f.st[i * 2] - M) * iS;
            }
            __syncthreads();
            if (tid < 16) ws[OFF_SCALES + ((long)t * 64 + b) * 16 + tid] = sm.f.sc[tid];
            float ctx = 0.f;
            #pragma unroll
            for (int i = 0; i < 16; ++i)
                ctx += sm.f.sc[i] * ldc(ws + OFF_CTXP + ((long)(b * 16 + i)) * 256 + tid);
            sm.f.cat[256 + tid] = ctx;
            sm.f.cat[tid] = ldc(ws + OFF_QUERY + (long)b * 256 + tid);
            stc(ws + OFF_RNN + (long)sn * 32768 + (long)b * HD + 256 + tid, ctx);
            __syncthreads();
            float a0 = b_mlp1[tid], a1 = b_mlp1[tid + 256];
            const float* Wm1 = ws + OFF_WM1;
            #pragma unroll 2
            for (int k4 = 0; k4 < 128; ++k4) {
                float4 x  = *reinterpret_cast<const float4*>(&sm.f.cat[k4 * 4]);
                float4 wA = *reinterpret_cast<const float4*>(Wm1 + ((long)k4 * 512 + tid) * 4);
                float4 wB = *reinterpret_cast<const float4*>(Wm1 + ((long)k4 * 512 + tid + 256) * 4);
                a0 += x.x * wA.x + x.y * wA.y + x.z * wA.z + x.w * wA.w;
                a1 += x.x * wB.x + x.y * wB.y + x.z * wB.z + x.w * wB.w;
            }
            sm.f.hm[tid]       = (a0 >= 0.f) ? a0 : 0.9f * a0;
            sm.f.hm[tid + 256] = (a1 >= 0.f) ? a1 : 0.9f * a1;
            __syncthreads();
            int w = tid >> 6, lane = tid & 63;
            if (lane < VV) {
                float acc = 0.f;
                const float* W2 = ws + OFF_WM2T;
                for (int m = w * 128; m < w * 128 + 128; ++m) acc += sm.f.hm[m] * W2[(long)m * VV + lane];
                sm.f.yp[w][lane] = acc;
            }
            __syncthreads();
            if (tid < VV) {
                float y = sm.f.yp[0][tid] + sm.f.yp[1][tid] + sm.f.yp[2][tid] + sm.f.yp[3][tid] + b_mlp2[tid];
                out[OUT_Y + ((long)b * TT + t) * VV + tid] = y;
                float u = gumbel_u[((long)t * BB + b) * VV + tid];
                float g = -logf(-logf(u + 1e-10f) + 1e-10f);
                sm.f.sv[tid] = y + g;
            }
            __syncthreads();
            if (tid == 0) {
                float mx = sm.f.sv[0]; int am = 0;
                for (int v = 1; v < VV; ++v) if (sm.f.sv[v] > mx) { mx = sm.f.sv[v]; am = v; }
                float Z = 0.f;
                for (int v = 0; v < VV; ++v) { float p = expf(sm.f.sv[v] - mx); sm.f.ysm[v] = p; Z += p; }
                float iz = 1.f / Z;
                for (int v = 0; v < VV; ++v) sm.f.ysm[v] *= iz;
                out[OUT_LBL + (long)b * TT + t] = (float)am;
            }
            __syncthreads();
            float acc = b_emb[tid];
            const float* We = ws + OFF_WEMBT;
            #pragma unroll
            for (int v = 0; v < VV; ++v) acc += sm.f.ysm[v] * We[(long)v * 256 + tid];
            stc(ws + OFF_RNN + (long)sn * 32768 + (long)b * HD + tid, acc);
        }
        gbar(wsbar, bx, ++bc);
    }
}

// ---------------- epilogues ----------------
__global__ __launch_bounds__(256) void k_labels(const int* __restrict__ lp, float* __restrict__ out)
{
    int id = blockIdx.x * 256 + threadIdx.x;
    if (id < BB * TT) {
        int b = id / TT, t = id % TT;
        out[OUT_LPT + id] = (float)lp[(long)t * BB + b];
    }
}

// full path: normalize (p * scale) + transpose [t][b*1024+l] -> out [b][l][t]
__global__ __launch_bounds__(256) void k_att_fin(const float* __restrict__ ws_ro,
                                                 float* __restrict__ out)
{
    __shared__ float tile[32][33];
    int blt = blockIdx.x, ttb = blockIdx.y;
    int tx = threadIdx.x & 31, ty = threadIdx.x >> 5;
    int bl0 = blt * 32, t0 = ttb * 32;
    int b = bl0 >> 10, ch = (bl0 & 1023) >> 6;
    #pragma unroll
    for (int jj = 0; jj < 4; ++jj) {
        int trow = t0 + ty + jj * 8;
        if (trow < TT) {
            float s = ws_ro[OFF_SCALES + ((long)trow * 64 + b) * 16 + ch];
            tile[ty + jj * 8][tx] = ws_ro[OFF_ATT + (long)trow * 65536 + bl0 + tx] * s;
        }
    }
    __syncthreads();
    #pragma unroll
    for (int jj = 0; jj < 4; ++jj) {
        int row = bl0 + ty + jj * 8;
        int col = t0 + tx;
        if (col < TT) out[OUT_ATT + (long)row * TT + col] = tile[tx][ty + jj * 8];
    }
}

// direct path: in-place scale of out[b][l][t]
__global__ __launch_bounds__(320) void k_att_scale(const float* __restrict__ ws_ro,
                                                    float* __restrict__ out)
{
    int bl = blockIdx.x;  // b*1024 + l
    int b = bl >> 10, ch = (bl & 1023) >> 6;
    int tid = threadIdx.x;
    if (tid < TT) {
        long base = OUT_ATT + (long)bl * TT;
        out[base + tid] *= ws_ro[OFF_SCALES + ((long)tid * 64 + b) * 16 + ch];
    }
}

extern "C" void kernel_launch(void* const* d_in, const int* in_sizes, int n_in,
                              void* d_out, int out_size, void* d_ws, size_t ws_size,
                              hipStream_t stream)
{
    const float* enc_key   = (const float*)d_in[0];
    const float* enc_value = (const float*)d_in[1];
    const int*   labels    = (const int*)d_in[2];
    const int*   fsl       = (const int*)d_in[3];
    const float* gumbel_u  = (const float*)d_in[4];
    const float* W_emb     = (const float*)d_in[5];
    const float* b_emb     = (const float*)d_in[6];
    const float* W_fc      = (const float*)d_in[7];
    const float* b_fc      = (const float*)d_in[8];
    const float* W_mlp1    = (const float*)d_in[9];
    const float* b_mlp1    = (const float*)d_in[10];
    const float* W_mlp2    = (const float*)d_in[11];
    const float* b_mlp2    = (const float*)d_in[12];
    const float* Wih0 = (const float*)d_in[13];
    const float* Whh0 = (const float*)d_in[14];
    const float* bih0 = (const float*)d_in[15];
    const float* bhh0 = (const float*)d_in[16];
    const float* Wih1 = (const float*)d_in[17];
    const float* Whh1 = (const float*)d_in[18];
    const float* bih1 = (const float*)d_in[19];
    const float* bhh1 = (const float*)d_in[20];
    const float* Wih2 = (const float*)d_in[21];
    const float* Whh2 = (const float*)d_in[22];
    const float* bih2 = (const float*)d_in[23];
    const float* bhh2 = (const float*)d_in[24];
    float* ws  = (float*)d_ws;
    float* out = (float*)d_out;

    const bool full = ws_size >= (size_t)WS_FLOATS_FULL * 4;
    float* attp = full ? (ws + OFF_ATT) : (out + OUT_ATT);
    const int attDirect = full ? 0 : 1;

    hipMemsetAsync((char*)d_ws + OFF_BAR * 4, 0, 4224 * 4, stream);
    hipLaunchKernelGGL(k_pack_gates, dim3(6168), dim3(256), 0, stream,
                       Wih0, Whh0, Wih1, Whh1, Wih2, Whh2,
                       bih0, bhh0, bih1, bhh1, bih2, bhh2, ws);
    hipLaunchKernelGGL(k_pack_small, dim3(483), dim3(256), 0, stream,
                       W_fc, W_mlp1, W_mlp2, W_emb, ws);
    hipLaunchKernelGGL(k_init, dim3(512), dim3(256), 0, stream, W_emb, b_emb, ws);

    hipLaunchKernelGGL(k_loop, dim3(NBLK), dim3(256), 0, stream,
                       enc_key, enc_value, fsl, gumbel_u, b_fc, b_mlp1, b_mlp2, b_emb,
                       ws, out, attp, attDirect);

    hipLaunchKernelGGL(k_labels, dim3(75), dim3(256), 0, stream, labels, out);
    if (full) hipLaunchKernelGGL(k_att_fin, dim3(2048, 10), dim3(256), 0, stream, ws, out);
    else      hipLaunchKernelGGL(k_att_scale, dim3(65536), dim3(320), 0, stream, ws, out);
}

// Round 5
// 88976.752 us; speedup vs baseline: 2.4571x; 1.0412x over previous
//
#include <hip/hip_runtime.h>
#include <math.h>

#define BB 64
#define LQ 1024
#define KVD 256
#define HD 512
#define ED 256
#define TT 300
#define VV 33
#define MHD 512
#define G4 2048
#define NBLK 1024
#define NGRP 32
#define GSZ 32

// ws float offsets
#define OFF_WPK     0L            // 6 x [128 k4][2048 r][4] packed gate weights
#define OFF_BIAS    6291456L      // 3*2048 combined bih+bhh, row r = m*4+g
#define OFF_WFC     6297600L      // [128 k4][256 kv][4]
#define OFF_WM1     6428672L      // [128 k4][512 m][4]
#define OFF_WM2T    6690816L      // [512][33]
#define OFF_WEMBT   6707712L      // [33][256]
#define OFF_H       6716160L      // [2 slot][3 layer][64][512]   (coherent)
#define OFF_C       6912768L      // block-private (cached)
#define OFF_RNN     7109376L      // [2 slot][64][512]            (coherent)
#define OFF_P1      7174912L      // [64][2048]                   (coherent)
#define OFF_P2      7305984L
#define OFF_QUERY   7437056L      // [64][256]                    (coherent)
#define OFF_STATS   7453440L      // [64][16][2]                  (coherent)
#define OFF_CTXP    7455488L      // [64][16][256]                (coherent)
#define OFF_SCALES  7717632L      // [300][64][16]
#define OFF_BAR     8024832L      // store/scan barrier: 17424 floats
#define OFF_ATT     8042256L      // [300][64][1024] unnormalized p
#define WS_FLOATS_FULL 27703056L

// out float offsets
#define OUT_Y      0L
#define OUT_LBL    633600L
#define OUT_LPT    652800L
#define OUT_ATT    672000L

// ---------------- MALL-coherent access helpers (bypass L1/L2) ----------------
__device__ __forceinline__ float ldc(const float* p) {
    unsigned u = __hip_atomic_load((const unsigned*)p, __ATOMIC_RELAXED, __HIP_MEMORY_SCOPE_AGENT);
    union { unsigned u; float f; } c; c.u = u; return c.f;
}
__device__ __forceinline__ void stc(float* p, float v) {
    union { float f; unsigned u; } c; c.f = v;
    __hip_atomic_store((unsigned*)p, c.u, __ATOMIC_RELAXED, __HIP_MEMORY_SCOPE_AGENT);
}
__device__ __forceinline__ float2 ldc2(const float* p) {
    unsigned long long u = __hip_atomic_load((const unsigned long long*)p,
                                             __ATOMIC_RELAXED, __HIP_MEMORY_SCOPE_AGENT);
    union { unsigned long long u; float2 f; } c; c.u = u; return c.f;
}
// 4x16B coherent loads issued back-to-back, single wait: 4-deep pipelined MALL access.
__device__ __forceinline__ void ldc4_batch4(const float* p0, const float* p1,
                                            const float* p2, const float* p3,
                                            float4& r0, float4& r1, float4& r2, float4& r3)
{
    asm volatile(
        "global_load_dwordx4 %0, %4, off sc0 sc1\n\t"
        "global_load_dwordx4 %1, %5, off sc0 sc1\n\t"
        "global_load_dwordx4 %2, %6, off sc0 sc1\n\t"
        "global_load_dwordx4 %3, %7, off sc0 sc1\n\t"
        "s_waitcnt vmcnt(0)"
        : "=&v"(r0), "=&v"(r1), "=&v"(r2), "=&v"(r3)
        : "v"(p0), "v"(p1), "v"(p2), "v"(p3)
        : "memory");
}

// ---------------- packing (once per call) ----------------
__global__ __launch_bounds__(256) void k_pack_gates(
    const float* __restrict__ Wih0, const float* __restrict__ Whh0,
    const float* __restrict__ Wih1, const float* __restrict__ Whh1,
    const float* __restrict__ Wih2, const float* __restrict__ Whh2,
    const float* __restrict__ bih0, const float* __restrict__ bhh0,
    const float* __restrict__ bih1, const float* __restrict__ bhh1,
    const float* __restrict__ bih2, const float* __restrict__ bhh2,
    float* __restrict__ ws)
{
    long id = (long)blockIdx.x * 256 + threadIdx.x;
    if (id < 6L * 262144L) {
        int mat = (int)(id / 262144L);
        int rem = (int)(id % 262144L);
        int k4 = rem >> 11;
        int r  = rem & 2047;
        int m = r >> 2, g = r & 3;
        int row = g * HD + m;
        const float* W = (mat==0)?Wih0:(mat==1)?Whh0:(mat==2)?Wih1:(mat==3)?Whh1:(mat==4)?Wih2:Whh2;
        const float4 v = *reinterpret_cast<const float4*>(W + (long)row * HD + k4 * 4);
        *reinterpret_cast<float4*>(ws + OFF_WPK + ((long)mat * 262144L + rem) * 4) = v;
    } else {
        long bid = id - 6L * 262144L;
        if (bid < 3L * 2048L) {
            int l = (int)(bid / 2048), r = (int)(bid % 2048);
            int m = r >> 2, g = r & 3;
            int row = g * HD + m;
            const float* bi = (l==0)?bih0:(l==1)?bih1:bih2;
            const float* bh = (l==0)?bhh0:(l==1)?bhh1:bhh2;
            ws[OFF_BIAS + bid] = bi[row] + bh[row];
        }
    }
}

__global__ __launch_bounds__(256) void k_pack_small(
    const float* __restrict__ W_fc, const float* __restrict__ W_mlp1,
    const float* __restrict__ W_mlp2, const float* __restrict__ W_emb,
    float* __restrict__ ws)
{
    int id = blockIdx.x * 256 + threadIdx.x;
    if (id < 32768) {
        int k4 = id >> 8, kv = id & 255;
        const float4 v = *reinterpret_cast<const float4*>(W_fc + (long)kv * HD + k4 * 4);
        *reinterpret_cast<float4*>(ws + OFF_WFC + (long)id * 4) = v;
        return;
    }
    id -= 32768;
    if (id < 65536) {
        int k4 = id >> 9, m = id & 511;
        const float4 v = *reinterpret_cast<const float4*>(W_mlp1 + (long)m * HD + k4 * 4);
        *reinterpret_cast<float4*>(ws + OFF_WM1 + (long)id * 4) = v;
        return;
    }
    id -= 65536;
    if (id < 512 * VV) {
        int m = id / VV, v = id % VV;
        ws[OFF_WM2T + id] = W_mlp2[(long)v * MHD + m];
        return;
    }
    id -= 512 * VV;
    if (id < VV * 256) {
        int v = id >> 8, e = id & 255;
        ws[OFF_WEMBT + id] = W_emb[(long)e * VV + v];
    }
}

__global__ __launch_bounds__(256) void k_init(
    const float* __restrict__ W_emb, const float* __restrict__ b_emb, float* __restrict__ ws)
{
    int id = blockIdx.x * 256 + threadIdx.x;
    if (id < 98304) { ws[OFF_H + id] = 0.f; ws[OFF_C + id] = 0.f; return; }
    id -= 98304;
    if (id < BB * HD) {
        int k = id & 511;
        float v = 0.f;
        if (k < ED) v = W_emb[(long)k * VV + 0] + b_emb[k];
        ws[OFF_RNN + id] = v;
    }
}

// ---------------- persistent loop kernel ----------------
struct SMGates { float in[32][132]; float g[8][33]; };
struct SMQuery { float h2[512]; float qp[4][64]; };
struct SMAttn  { float eL[64]; float pL[64]; };
struct SMFin   { float cat[512]; float hm[512]; float yp[4][33]; float sv[33];
                 float ysm[33]; float sc[16]; float st[32]; };
union SMU { SMGates g; SMQuery q; SMAttn a; SMFin f; };

// Store/scan tree barrier: no RMW serialization anywhere.
// slots[g][i] at (g*32+i)*16 floats; gdone[g] at 16384+g*16; go at 16896;
// grpgo[g] at 16912+g*16. All 64B-spaced, monotonic epochs, memset at launch.
__device__ __forceinline__ void gbar(float* wsbar, int bx, unsigned bc)
{
    asm volatile("s_waitcnt vmcnt(0)" ::: "memory");
    __syncthreads();
    int g = bx >> 5, i = bx & 31;
    unsigned* slots = (unsigned*)wsbar;
    unsigned* gdone = (unsigned*)(wsbar + 16384);
    unsigned* go    = (unsigned*)(wsbar + 16896);
    unsigned* grpgo = (unsigned*)(wsbar + 16912);
    int tid = threadIdx.x;
    if (tid < 64) {
        if (tid == 0)
            __hip_atomic_store(slots + ((long)g * 32 + i) * 16, bc,
                               __ATOMIC_RELAXED, __HIP_MEMORY_SCOPE_AGENT);
        if (i == 0) {
            for (;;) {   // scan my group's 32 slots with 32 lanes
                unsigned v = 0;
                if (tid < 32)
                    v = __hip_atomic_load(slots + ((long)g * 32 + tid) * 16,
                                          __ATOMIC_RELAXED, __HIP_MEMORY_SCOPE_AGENT);
                if (__all(tid >= 32 || v >= bc)) break;
                __builtin_amdgcn_s_sleep(1);
            }
            if (tid == 0)
                __hip_atomic_store(gdone + (long)g * 16, bc,
                                   __ATOMIC_RELAXED, __HIP_MEMORY_SCOPE_AGENT);
            if (g == 0) {
                for (;;) {   // root: scan 32 group-done slots
                    unsigned d = 0;
                    if (tid < 32)
                        d = __hip_atomic_load(gdone + (long)tid * 16,
                                              __ATOMIC_RELAXED, __HIP_MEMORY_SCOPE_AGENT);
                    if (__all(tid >= 32 || d >= bc)) break;
                    __builtin_amdgcn_s_sleep(1);
                }
                if (tid == 0)
                    __hip_atomic_store(go, bc, __ATOMIC_RELAXED, __HIP_MEMORY_SCOPE_AGENT);
            } else if (tid == 0) {
                while (__hip_atomic_load(go, __ATOMIC_RELAXED, __HIP_MEMORY_SCOPE_AGENT) < bc)
                    __builtin_amdgcn_s_sleep(1);
            }
            if (tid == 0)
                __hip_atomic_store(grpgo + (long)g * 16, bc,
                                   __ATOMIC_RELAXED, __HIP_MEMORY_SCOPE_AGENT);
        } else if (tid == 0) {
            while (__hip_atomic_load(grpgo + (long)g * 16, __ATOMIC_RELAXED,
                                     __HIP_MEMORY_SCOPE_AGENT) < bc)
                __builtin_amdgcn_s_sleep(1);
        }
    }
    __syncthreads();
}

// 8 rows x 32 batch tile MAC with batched coherent staging (4x16B per thread/chunk).
__device__ __forceinline__ void gmac8(float& acc, const float* inp, const float* Wpk,
                                      int r0, int jl, int bg, float (*lin)[132], int tid)
{
    int b0 = tid >> 5, k0 = tid & 31;
    for (int kc = 0; kc < 4; ++kc) {
        const float* base = inp + kc * 128 + (long)b0 * HD + k0 * 4;
        float4 s0, s1, s2, s3;
        ldc4_batch4(base, base + 8 * HD, base + 16 * HD, base + 24 * HD, s0, s1, s2, s3);
        __syncthreads();
        *reinterpret_cast<float4*>(&lin[b0][k0 * 4])      = s0;
        *reinterpret_cast<float4*>(&lin[b0 + 8][k0 * 4])  = s1;
        *reinterpret_cast<float4*>(&lin[b0 + 16][k0 * 4]) = s2;
        *reinterpret_cast<float4*>(&lin[b0 + 24][k0 * 4]) = s3;
        __syncthreads();
        const float* Wb = Wpk + ((long)(kc * 32) * G4 + (r0 + jl)) * 4;
        #pragma unroll 8
        for (int k4 = 0; k4 < 32; ++k4) {
            float4 w = *reinterpret_cast<const float4*>(Wb + (long)k4 * G4 * 4);
            float4 x = *reinterpret_cast<const float4*>(&lin[bg][k4 * 4]);
            acc += x.x * w.x + x.y * w.y + x.z * w.z + x.w * w.w;
        }
    }
}

__device__ __forceinline__ void cell8(float acc, int r0, int tid,
    const float* c_old, float* c_new, float* h_new, float (*g)[33])
{
    g[tid & 7][tid >> 3] = acc;
    __syncthreads();
    if (tid < 64) {
        int ml = tid >> 5, bl = tid & 31;
        int m = (r0 >> 2) + ml;
        float gi = g[ml * 4 + 0][bl];
        float gf = g[ml * 4 + 1][bl];
        float gg = g[ml * 4 + 2][bl];
        float go = g[ml * 4 + 3][bl];
        float si = 1.f / (1.f + expf(-gi));
        float sf = 1.f / (1.f + expf(-gf));
        float tg = tanhf(gg);
        float so = 1.f / (1.f + expf(-go));
        float c2 = sf * c_old[(long)bl * HD + m] + si * tg;   // c: block-private, cached
        c_new[(long)bl * HD + m] = c2;
        stc(h_new + (long)bl * HD + m, so * tanhf(c2));       // h: shared, coherent
    }
    __syncthreads();
}

__global__ __launch_bounds__(256, 4) void k_loop(
    const float* __restrict__ enc_key, const float* __restrict__ enc_value,
    const int* __restrict__ fsl, const float* __restrict__ gumbel_u,
    const float* __restrict__ b_fc, const float* __restrict__ b_mlp1,
    const float* __restrict__ b_mlp2, const float* __restrict__ b_emb,
    float* ws, float* out, float* attp, int attDirect)
{
    __shared__ SMU sm;
    int bx = blockIdx.x, tid = threadIdx.x;
    float* wsbar = ws + OFF_BAR;
    unsigned bc = 0;

    for (int t = 0; t < TT; ++t) {
        int so = t & 1, sn = so ^ 1;

        // ---- PHASE A: L0 full gates + Whh partials L1,L2 ----
        if (bx < 512) {
            int px = bx >> 1, bh = bx & 1, r0 = px * 8;
            int jl = tid & 7, bg = tid >> 3;
            float acc = ws[OFF_BIAS + r0 + jl];
            const float* rnn = ws + OFF_RNN + (long)so * 32768 + (long)bh * 32 * HD;
            const float* h0  = ws + OFF_H + ((long)so * 3 + 0) * 32768 + (long)bh * 32 * HD;
            gmac8(acc, rnn, ws + OFF_WPK + 0L * 1048576L, r0, jl, bg, sm.g.in, tid);
            gmac8(acc, h0,  ws + OFF_WPK + 1L * 1048576L, r0, jl, bg, sm.g.in, tid);
            cell8(acc, r0, tid,
                  ws + OFF_C + ((long)so * 3 + 0) * 32768 + (long)bh * 32 * HD,
                  ws + OFF_C + ((long)sn * 3 + 0) * 32768 + (long)bh * 32 * HD,
                  ws + OFF_H + ((long)sn * 3 + 0) * 32768 + (long)bh * 32 * HD, sm.g.g);
        } else {
            int u = bx - 512;
            int px = u >> 1, bh = u & 1, r0 = px * 8;
            int jl = tid & 7, bg = tid >> 3;
            {
                float acc = ws[OFF_BIAS + 2048 + r0 + jl];
                const float* h1 = ws + OFF_H + ((long)so * 3 + 1) * 32768 + (long)bh * 32 * HD;
                gmac8(acc, h1, ws + OFF_WPK + 3L * 1048576L, r0, jl, bg, sm.g.in, tid);
                stc(ws + OFF_P1 + (long)(bh * 32 + bg) * G4 + r0 + jl, acc);
            }
            {
                float acc = ws[OFF_BIAS + 4096 + r0 + jl];
                const float* h2 = ws + OFF_H + ((long)so * 3 + 2) * 32768 + (long)bh * 32 * HD;
                gmac8(acc, h2, ws + OFF_WPK + 5L * 1048576L, r0, jl, bg, sm.g.in, tid);
                stc(ws + OFF_P2 + (long)(bh * 32 + bg) * G4 + r0 + jl, acc);
            }
        }
        gbar(wsbar, bx, ++bc);

        // ---- PHASE B: LSTM layer 1 ----
        if (bx < 512) {
            int px = bx >> 1, bh = bx & 1, r0 = px * 8;
            int jl = tid & 7, bg = tid >> 3;
            float acc = ldc(ws + OFF_P1 + (long)(bh * 32 + bg) * G4 + r0 + jl);
            const float* h0n = ws + OFF_H + ((long)sn * 3 + 0) * 32768 + (long)bh * 32 * HD;
            gmac8(acc, h0n, ws + OFF_WPK + 2L * 1048576L, r0, jl, bg, sm.g.in, tid);
            cell8(acc, r0, tid,
                  ws + OFF_C + ((long)so * 3 + 1) * 32768 + (long)bh * 32 * HD,
                  ws + OFF_C + ((long)sn * 3 + 1) * 32768 + (long)bh * 32 * HD,
                  ws + OFF_H + ((long)sn * 3 + 1) * 32768 + (long)bh * 32 * HD, sm.g.g);
        }
        gbar(wsbar, bx, ++bc);

        // ---- PHASE C: LSTM layer 2 ----
        if (bx < 512) {
            int px = bx >> 1, bh = bx & 1, r0 = px * 8;
            int jl = tid & 7, bg = tid >> 3;
            float acc = ldc(ws + OFF_P2 + (long)(bh * 32 + bg) * G4 + r0 + jl);
            const float* h1n = ws + OFF_H + ((long)sn * 3 + 1) * 32768 + (long)bh * 32 * HD;
            gmac8(acc, h1n, ws + OFF_WPK + 4L * 1048576L, r0, jl, bg, sm.g.in, tid);
            cell8(acc, r0, tid,
                  ws + OFF_C + ((long)so * 3 + 2) * 32768 + (long)bh * 32 * HD,
                  ws + OFF_C + ((long)sn * 3 + 2) * 32768 + (long)bh * 32 * HD,
                  ws + OFF_H + ((long)sn * 3 + 2) * 32768 + (long)bh * 32 * HD, sm.g.g);
        }
        gbar(wsbar, bx, ++bc);

        // ---- PHASE D: query = h2 @ Wfc^T + b_fc (256 blocks: b x kq) ----
        if (bx < 256) {
            int b = bx >> 2, kq = bx & 3;
            const float* h2p = ws + OFF_H + ((long)sn * 3 + 2) * 32768 + (long)b * HD;
            { float2 v = ldc2(h2p + tid * 2); *reinterpret_cast<float2*>(&sm.q.h2[tid * 2]) = v; }
            __syncthreads();
            int o = tid & 63, kh = tid >> 6;
            float acc = 0.f;
            const float* Wf = ws + OFF_WFC;
            #pragma unroll 4
            for (int k4i = 0; k4i < 32; ++k4i) {
                int k4 = kh * 32 + k4i;
                float4 wv = *reinterpret_cast<const float4*>(Wf + ((long)k4 * 256 + kq * 64 + o) * 4);
                float4 x  = *reinterpret_cast<const float4*>(&sm.q.h2[k4 * 4]);
                acc += x.x * wv.x + x.y * wv.y + x.z * wv.z + x.w * wv.w;
            }
            sm.q.qp[kh][o] = acc;
            __syncthreads();
            if (tid < 64) {
                float q = sm.q.qp[0][tid] + sm.q.qp[1][tid] + sm.q.qp[2][tid] + sm.q.qp[3][tid]
                          + b_fc[kq * 64 + tid];
                stc(ws + OFF_QUERY + (long)b * 256 + kq * 64 + tid, q);
            }
        }
        gbar(wsbar, bx, ++bc);

        // ---- PHASE E: attention single pass (1024 blocks: b x 16 chunks of 64 l) ----
        {
            int b = bx >> 4, ch = bx & 15, l0 = ch * 64;
            int lane = tid & 63, w = tid >> 6;
            int j = lane & 15, rq = lane >> 4;
            const float* qb = ws + OFF_QUERY + (long)b * 256 + j * 4;
            float4 q4[4];
            ldc4_batch4(qb, qb + 64, qb + 128, qb + 192, q4[0], q4[1], q4[2], q4[3]);
            int n = fsl[b];
            for (int qq = 0; qq < 4; ++qq) {
                int l = l0 + w * 16 + qq * 4 + rq;
                const float* Kr = enc_key + ((long)(b * LQ + l)) * KVD;
                float s = 0.f;
                #pragma unroll
                for (int kk = 0; kk < 4; ++kk) {
                    float4 kv = *reinterpret_cast<const float4*>(Kr + kk * 64 + j * 4);
                    s += kv.x * q4[kk].x + kv.y * q4[kk].y + kv.z * q4[kk].z + kv.w * q4[kk].w;
                }
                s += __shfl_xor(s, 1, 64); s += __shfl_xor(s, 2, 64);
                s += __shfl_xor(s, 4, 64); s += __shfl_xor(s, 8, 64);
                float e = (l < n) ? s : 0.f;   // softmax(energy*mask): masked -> exp(0)
                if (j == 0) sm.a.eL[w * 16 + qq * 4 + rq] = e;
            }
            __syncthreads();
            if (w == 0) {
                float e = sm.a.eL[lane];
                float m = e;
                m = fmaxf(m, __shfl_xor(m, 1, 64));  m = fmaxf(m, __shfl_xor(m, 2, 64));
                m = fmaxf(m, __shfl_xor(m, 4, 64));  m = fmaxf(m, __shfl_xor(m, 8, 64));
                m = fmaxf(m, __shfl_xor(m, 16, 64)); m = fmaxf(m, __shfl_xor(m, 32, 64));
                float p = expf(e - m);
                sm.a.pL[lane] = p;
                float su = p;
                su += __shfl_xor(su, 1, 64);  su += __shfl_xor(su, 2, 64);
                su += __shfl_xor(su, 4, 64);  su += __shfl_xor(su, 8, 64);
                su += __shfl_xor(su, 16, 64); su += __shfl_xor(su, 32, 64);
                if (attDirect) attp[((long)(b * LQ + l0 + lane)) * TT + t] = p;
                else           attp[(long)t * 65536 + b * LQ + l0 + lane] = p;
                if (lane == 0) {
                    stc(ws + OFF_STATS + ((long)(b * 16 + ch)) * 2 + 0, m);
                    stc(ws + OFF_STATS + ((long)(b * 16 + ch)) * 2 + 1, su);
                }
            }
            __syncthreads();
            float acc = 0.f;
            const float* Vb = enc_value + ((long)(b * LQ + l0)) * KVD + tid;
            #pragma unroll 8
            for (int i = 0; i < 64; ++i) acc += sm.a.pL[i] * Vb[(long)i * KVD];
            stc(ws + OFF_CTXP + ((long)(b * 16 + ch)) * 256 + tid, acc);
        }
        gbar(wsbar, bx, ++bc);

        // ---- PHASE F: combine + MLP + gumbel + argmax + emb (64 blocks) ----
        if (bx < 64) {
            int b = bx;
            if (tid < 32) sm.f.st[tid] = ldc(ws + OFF_STATS + (long)b * 32 + tid);
            __syncthreads();
            if (tid == 0) {
                float M = -3.4e38f;
                for (int i = 0; i < 16; ++i) M = fmaxf(M, sm.f.st[i * 2]);
                float S = 0.f;
                for (int i = 0; i < 16; ++i) S += sm.f.st[i * 2 + 1] * expf(sm.f.st[i * 2] - M);
                float iS = 1.f / S;
                for (int i = 0; i < 16; ++i) sm.f.sc[i] = expf(sm.f.st[i * 2] - M) * iS;
            }
            __syncthreads();
            if (tid < 16) ws[OFF_SCALES + ((long)t * 64 + b) * 16 + tid] = sm.f.sc[tid];
            float ctx = 0.f;
            #pragma unroll
            for (int i = 0; i < 16; ++i)
                ctx += sm.f.sc[i] * ldc(ws + OFF_CTXP + ((long)(b * 16 + i)) * 256 + tid);
            sm.f.cat[256 + tid] = ctx;
            sm.f.cat[tid] = ldc(ws + OFF_QUERY + (long)b * 256 + tid);
            stc(ws + OFF_RNN + (long)sn * 32768 + (long)b * HD + 256 + tid, ctx);
            __syncthreads();
            float a0 = b_mlp1[tid], a1 = b_mlp1[tid + 256];
            const float* Wm1 = ws + OFF_WM1;
            #pragma unroll 4
            for (int k4 = 0; k4 < 128; ++k4) {
                float4 x  = *reinterpret_cast<const float4*>(&sm.f.cat[k4 * 4]);
                float4 wA = *reinterpret_cast<const float4*>(Wm1 + ((long)k4 * 512 + tid) * 4);
                float4 wB = *reinterpret_cast<const float4*>(Wm1 + ((long)k4 * 512 + tid + 256) * 4);
                a0 += x.x * wA.x + x.y * wA.y + x.z * wA.z + x.w * wA.w;
                a1 += x.x * wB.x + x.y * wB.y + x.z * wB.z + x.w * wB.w;
            }
            sm.f.hm[tid]       = (a0 >= 0.f) ? a0 : 0.9f * a0;
            sm.f.hm[tid + 256] = (a1 >= 0.f) ? a1 : 0.9f * a1;
            __syncthreads();
            int w = tid >> 6, lane = tid & 63;
            if (lane < VV) {
                float acc = 0.f;
                const float* W2 = ws + OFF_WM2T;
                for (int m = w * 128; m < w * 128 + 128; ++m) acc += sm.f.hm[m] * W2[(long)m * VV + lane];
                sm.f.yp[w][lane] = acc;
            }
            __syncthreads();
            if (tid < VV) {
                float y = sm.f.yp[0][tid] + sm.f.yp[1][tid] + sm.f.yp[2][tid] + sm.f.yp[3][tid] + b_mlp2[tid];
                out[OUT_Y + ((long)b * TT + t) * VV + tid] = y;
                float u = gumbel_u[((long)t * BB + b) * VV + tid];
                float g = -logf(-logf(u + 1e-10f) + 1e-10f);
                sm.f.sv[tid] = y + g;
            }
            __syncthreads();
            if (tid == 0) {
                float mx = sm.f.sv[0]; int am = 0;
                for (int v = 1; v < VV; ++v) if (sm.f.sv[v] > mx) { mx = sm.f.sv[v]; am = v; }
                float Z = 0.f;
                for (int v = 0; v < VV; ++v) { float p = expf(sm.f.sv[v] - mx); sm.f.ysm[v] = p; Z += p; }
                float iz = 1.f / Z;
                for (int v = 0; v < VV; ++v) sm.f.ysm[v] *= iz;
                out[OUT_LBL + (long)b * TT + t] = (float)am;
            }
            __syncthreads();
            float acc = b_emb[tid];
            const float* We = ws + OFF_WEMBT;
            #pragma unroll
            for (int v = 0; v < VV; ++v) acc += sm.f.ysm[v] * We[(long)v * 256 + tid];
            stc(ws + OFF_RNN + (long)sn * 32768 + (long)b * HD + tid, acc);
        }
        gbar(wsbar, bx, ++bc);
    }
}

// ---------------- epilogues ----------------
__global__ __launch_bounds__(256) void k_labels(const int* __restrict__ lp, float* __restrict__ out)
{
    int id = blockIdx.x * 256 + threadIdx.x;
    if (id < BB * TT) {
        int b = id / TT, t = id % TT;
        out[OUT_LPT + id] = (float)lp[(long)t * BB + b];
    }
}

// full path: normalize (p * scale) + transpose [t][b*1024+l] -> out [b][l][t]
__global__ __launch_bounds__(256) void k_att_fin(const float* __restrict__ ws_ro,
                                                 float* __restrict__ out)
{
    __shared__ float tile[32][33];
    int blt = blockIdx.x, ttb = blockIdx.y;
    int tx = threadIdx.x & 31, ty = threadIdx.x >> 5;
    int bl0 = blt * 32, t0 = ttb * 32;
    int b = bl0 >> 10, ch = (bl0 & 1023) >> 6;
    #pragma unroll
    for (int jj = 0; jj < 4; ++jj) {
        int trow = t0 + ty + jj * 8;
        if (trow < TT) {
            float s = ws_ro[OFF_SCALES + ((long)trow * 64 + b) * 16 + ch];
            tile[ty + jj * 8][tx] = ws_ro[OFF_ATT + (long)trow * 65536 + bl0 + tx] * s;
        }
    }
    __syncthreads();
    #pragma unroll
    for (int jj = 0; jj < 4; ++jj) {
        int row = bl0 + ty + jj * 8;
        int col = t0 + tx;
        if (col < TT) out[OUT_ATT + (long)row * TT + col] = tile[tx][ty + jj * 8];
    }
}

// direct path: in-place scale of out[b][l][t]
__global__ __launch_bounds__(320) void k_att_scale(const float* __restrict__ ws_ro,
                                                    float* __restrict__ out)
{
    int bl = blockIdx.x;  // b*1024 + l
    int b = bl >> 10, ch = (bl & 1023) >> 6;
    int tid = threadIdx.x;
    if (tid < TT) {
        long base = OUT_ATT + (long)bl * TT;
        out[base + tid] *= ws_ro[OFF_SCALES + ((long)tid * 64 + b) * 16 + ch];
    }
}

extern "C" void kernel_launch(void* const* d_in, const int* in_sizes, int n_in,
                              void* d_out, int out_size, void* d_ws, size_t ws_size,
                              hipStream_t stream)
{
    const float* enc_key   = (const float*)d_in[0];
    const float* enc_value = (const float*)d_in[1];
    const int*   labels    = (const int*)d_in[2];
    const int*   fsl       = (const int*)d_in[3];
    const float* gumbel_u  = (const float*)d_in[4];
    const float* W_emb     = (const float*)d_in[5];
    const float* b_emb     = (const float*)d_in[6];
    const float* W_fc      = (const float*)d_in[7];
    const float* b_fc      = (const float*)d_in[8];
    const float* W_mlp1    = (const float*)d_in[9];
    const float* b_mlp1    = (const float*)d_in[10];
    const float* W_mlp2    = (const float*)d_in[11];
    const float* b_mlp2    = (const float*)d_in[12];
    const float* Wih0 = (const float*)d_in[13];
    const float* Whh0 = (const float*)d_in[14];
    const float* bih0 = (const float*)d_in[15];
    const float* bhh0 = (const float*)d_in[16];
    const float* Wih1 = (const float*)d_in[17];
    const float* Whh1 = (const float*)d_in[18];
    const float* bih1 = (const float*)d_in[19];
    const float* bhh1 = (const float*)d_in[20];
    const float* Wih2 = (const float*)d_in[21];
    const float* Whh2 = (const float*)d_in[22];
    const float* bih2 = (const float*)d_in[23];
    const float* bhh2 = (const float*)d_in[24];
    float* ws  = (float*)d_ws;
    float* out = (float*)d_out;

    const bool full = ws_size >= (size_t)WS_FLOATS_FULL * 4;
    float* attp = full ? (ws + OFF_ATT) : (out + OUT_ATT);
    const int attDirect = full ? 0 : 1;

    hipMemsetAsync((char*)d_ws + OFF_BAR * 4, 0, 17424 * 4, stream);
    hipLaunchKernelGGL(k_pack_gates, dim3(6168), dim3(256), 0, stream,
                       Wih0, Whh0, Wih1, Whh1, Wih2, Whh2,
                       bih0, bhh0, bih1, bhh1, bih2, bhh2, ws);
    hipLaunchKernelGGL(k_pack_small, dim3(483), dim3(256), 0, stream,
                       W_fc, W_mlp1, W_mlp2, W_emb, ws);
    hipLaunchKernelGGL(k_init, dim3(512), dim3(256), 0, stream, W_emb, b_emb, ws);

    hipLaunchKernelGGL(k_loop, dim3(NBLK), dim3(256), 0, stream,
                       enc_key, enc_value, fsl, gumbel_u, b_fc, b_mlp1, b_mlp2, b_emb,
                       ws, out, attp, attDirect);

    hipLaunchKernelGGL(k_labels, dim3(75), dim3(256), 0, stream, labels, out);
    if (full) hipLaunchKernelGGL(k_att_fin, dim3(2048, 10), dim3(256), 0, stream, ws, out);
    else      hipLaunchKernelGGL(k_att_scale, dim3(65536), dim3(320), 0, stream, ws, out);
}